// Round 4
// baseline (236.262 us; speedup 1.0000x reference)
//
#include <hip/hip_runtime.h>
#include <hip/hip_bf16.h>

using ushort_t = unsigned short;
using f32x4  = __attribute__((ext_vector_type(4))) float;
using short8 = __attribute__((ext_vector_type(8))) short;

// ---------- bf16 helpers ----------
__device__ __forceinline__ float bflo(unsigned p) {
    union { unsigned u; float f; } x; x.u = p << 16; return x.f;
}
__device__ __forceinline__ float bfhi(unsigned p) {
    union { unsigned u; float f; } x; x.u = p & 0xffff0000u; return x.f;
}
__device__ __forceinline__ ushort_t f2bf(float f) {
    __hip_bfloat16 h = __float2bfloat16(f);   // RTNE
    return *(ushort_t*)&h;
}
__device__ __forceinline__ unsigned pk2bf(float lo, float hi) {
    __hip_bfloat162 h = __float22bfloat162_rn({lo, hi});  // RTNE, packed
    return *(unsigned*)&h;
}

// ---------- combined weight prep ----------
__device__ __forceinline__ void tr_tile(const float* __restrict__ S, ushort_t* __restrict__ D,
                                        int K, int N, int Npad, int bx, int by,
                                        int tx, int ty, float* tile /*32*33*/)
{
    const int k0 = by * 32, n0 = bx * 32;
#pragma unroll
    for (int r = 0; r < 4; r++) {
        const int k = k0 + ty + r * 8, n = n0 + tx;
        tile[(ty + r * 8) * 33 + tx] = (k < K && n < N) ? S[(size_t)k * N + n] : 0.f;
    }
    __syncthreads();
#pragma unroll
    for (int r = 0; r < 4; r++) {
        const int n = n0 + ty + r * 8, k = k0 + tx;
        if (n < Npad && k < K) D[(size_t)n * K + k] = f2bf(tile[tx * 33 + ty + r * 8]);
    }
}

// fp32 -> fp32 transpose (for clf_W): D[n][k] = S[k][n], K=1024, N=500
__device__ __forceinline__ void trf_tile(const float* __restrict__ S, float* __restrict__ D,
                                         int K, int N, int bx, int by,
                                         int tx, int ty, float* tile /*32*33*/)
{
    const int k0 = by * 32, n0 = bx * 32;
#pragma unroll
    for (int r = 0; r < 4; r++) {
        const int k = k0 + ty + r * 8, n = n0 + tx;
        tile[(ty + r * 8) * 33 + tx] = (k < K && n < N) ? S[(size_t)k * N + n] : 0.f;
    }
    __syncthreads();
#pragma unroll
    for (int r = 0; r < 4; r++) {
        const int n = n0 + ty + r * 8, k = k0 + tx;
        if (n < N && k < K) D[(size_t)n * K + k] = tile[tx * 33 + ty + r * 8];
    }
}

__global__ __launch_bounds__(256)
void prep_weights(const float* __restrict__ Wobj, ushort_t* __restrict__ WobjT,
                  const float* __restrict__ Wact, ushort_t* __restrict__ WactT,
                  const float* __restrict__ fc1W, ushort_t* __restrict__ fc1T,
                  const float* __restrict__ gc1W, ushort_t* __restrict__ W1t,
                  const float* __restrict__ gc3W, ushort_t* __restrict__ W3t,
                  const float* __restrict__ gc2W, ushort_t* __restrict__ W2bf,
                  const float* __restrict__ gc4W, ushort_t* __restrict__ W4bf,
                  const float* __restrict__ clfW, float* __restrict__ WclfT)
{
    __shared__ float tile[32 * 33];
    const int b = blockIdx.x;
    const int t = threadIdx.x;
    const int tx = t & 31, ty = t >> 5;

    if (b < 1056) {
        const float* S; ushort_t* D; int K, N, Npad, nt, l;
        if      (b < 256)  { S = Wobj; D = WobjT; K = 512; N = 512;  Npad = 512;  nt = 16; l = b; }
        else if (b < 512)  { S = Wact; D = WactT; K = 512; N = 512;  Npad = 512;  nt = 16; l = b - 256; }
        else if (b < 1024) { S = fc1W; D = fc1T;  K = 512; N = 1024; Npad = 1024; nt = 32; l = b - 512; }
        else if (b < 1040) { S = gc1W; D = W1t;   K = 512; N = 32;   Npad = 32;   nt = 1;  l = b - 1024; }
        else               { S = gc3W; D = W3t;   K = 512; N = 32;   Npad = 32;   nt = 1;  l = b - 1040; }
        tr_tile(S, D, K, N, Npad, l % nt, l / nt, tx, ty, tile);
    } else if (b < 1072) {
        const float* S = (b < 1064) ? gc2W : gc4W;
        ushort_t* D    = (b < 1064) ? W2bf : W4bf;
        const int i = (b < 1064 ? b - 1056 : b - 1064) * 256 + t;
        const float4 x = ((const float4*)S)[2 * i];
        const float4 y = ((const float4*)S)[2 * i + 1];
        unsigned r[4] = { pk2bf(x.x, x.y), pk2bf(x.z, x.w), pk2bf(y.x, y.y), pk2bf(y.z, y.w) };
        ((uint4*)D)[i] = *(uint4*)r;
    } else {
        const int l = b - 1072;
        trf_tile(clfW, WclfT, 1024, 500, l & 15, l >> 4, tx, ty, tile);
    }
}

// ---------- obj GEMM v3 (r2-proven): 128-row A tile, transaction-minimized ----------
__global__ __launch_bounds__(512, 2)
void gemm_obj_stream(const float* __restrict__ A, const ushort_t* __restrict__ Bt,
                     const float* __restrict__ bias, ushort_t* __restrict__ C)
{
    __shared__ __align__(16) ushort_t As[128 * 512];   // 128KB, reused as C stage
    const int t = threadIdx.x;
    const int lane = t & 63, w = t >> 6;              // w in 0..7
    const int bm = blockIdx.x * 128;
    const int fr = lane & 15, fq = lane >> 4;

    const float4* A4 = (const float4*)(A + (size_t)bm * 512);
#pragma unroll
    for (int i = 0; i < 16; i++) {
        const int fl = i * 1024 + t * 2;
        const int row = fl >> 7;
        const float4 p0 = A4[fl];
        const float4 p1 = A4[fl + 1];
        unsigned rr[4] = { pk2bf(p0.x, p0.y), pk2bf(p0.z, p0.w),
                           pk2bf(p1.x, p1.y), pk2bf(p1.z, p1.w) };
        *(uint4*)&As[row * 512 + ((lane ^ (row & 7)) * 8)] = *(uint4*)rr;
    }

    const int nw = w * 64;
    const ushort_t* Bbase = Bt + (size_t)(nw + fr) * 512 + fq * 8;

    uint4 bA[4], bB[4];
#pragma unroll
    for (int j = 0; j < 4; j++) bA[j] = *(const uint4*)(Bbase + (size_t)j * 16 * 512);

    __syncthreads();

    f32x4 acc[4][8];
#pragma unroll
    for (int j = 0; j < 4; j++)
#pragma unroll
        for (int i = 0; i < 8; i++) acc[j][i] = (f32x4){0.f, 0.f, 0.f, 0.f};

    for (int kk = 0; kk < 16; kk += 2) {
        short8 af[8];
#pragma unroll
        for (int i = 0; i < 8; i++)
            af[i] = *(const short8*)&As[(i * 16 + fr) * 512 + (((kk * 4 + fq) ^ (fr & 7)) * 8)];
#pragma unroll
        for (int j = 0; j < 4; j++) {
            bB[j] = *(const uint4*)(Bbase + (size_t)j * 16 * 512 + (kk + 1) * 32);
            const short8 bf = *(const short8*)&bA[j];
#pragma unroll
            for (int i = 0; i < 8; i++)
                acc[j][i] = __builtin_amdgcn_mfma_f32_16x16x32_bf16(af[i], bf, acc[j][i], 0, 0, 0);
        }
#pragma unroll
        for (int i = 0; i < 8; i++)
            af[i] = *(const short8*)&As[(i * 16 + fr) * 512 + ((((kk + 1) * 4 + fq) ^ (fr & 7)) * 8)];
#pragma unroll
        for (int j = 0; j < 4; j++) {
            if (kk + 2 < 16)
                bA[j] = *(const uint4*)(Bbase + (size_t)j * 16 * 512 + (kk + 2) * 32);
            const short8 bf = *(const short8*)&bB[j];
#pragma unroll
            for (int i = 0; i < 8; i++)
                acc[j][i] = __builtin_amdgcn_mfma_f32_16x16x32_bf16(af[i], bf, acc[j][i], 0, 0, 0);
        }
    }

    __syncthreads();
#pragma unroll
    for (int j = 0; j < 4; j++) {
        const int col0 = j * 16 + fr;
        const float bv = bias[nw + col0];
#pragma unroll
        for (int i = 0; i < 8; i++) {
#pragma unroll
            for (int rr2 = 0; rr2 < 4; rr2++) {
                const int m = i * 16 + fq * 4 + rr2;
                const int pc = col0 ^ (((m >> 2) & 3) << 4);
                As[m * 512 + nw + pc] = f2bf(fmaxf(acc[j][i][rr2] + bv, 0.f));
            }
        }
    }
    __syncthreads();
#pragma unroll
    for (int i2 = 0; i2 < 16; i2++) {
        const int fl = i2 * 512 + t;
        const int m  = fl >> 6;
        const int n0 = (fl & 63) * 8;
        const int sl = n0 & ~63;
        const int cl = n0 & 63;
        const uint4 v = *(const uint4*)&As[m * 512 + sl + (cl ^ (((m >> 2) & 3) << 4))];
        *(uint4*)&C[(size_t)(bm + m) * 512 + n0] = v;
    }
}

// ---------- generic MFMA GEMM (barrier structure, proven for act) ----------
typedef __attribute__((address_space(1))) void glb_void;
typedef __attribute__((address_space(3))) void lds_void;
__device__ __forceinline__ void dma16(const void* g, void* l) {
    __builtin_amdgcn_global_load_lds((glb_void*)(unsigned long long)(uintptr_t)g,
                                     (lds_void*)(unsigned)(uintptr_t)l, 16, 0, 0);
}

template<int RELU, typename AT>
__global__ __launch_bounds__(256)
void gemm_dma(const AT* __restrict__ A, const ushort_t* __restrict__ Bt,
              const float* __restrict__ bias, ushort_t* __restrict__ C,
              int N, int K, int Nb, int row_mul, int row_add)
{
    __shared__ __align__(16) char     AsRaw[128 * 32 * sizeof(AT)];
    __shared__ __align__(16) ushort_t Bs[128 * 32];
    const int t = threadIdx.x;
    const int lane = t & 63, w = t >> 6;
    const int bm = blockIdx.y * 128, bn = blockIdx.x * 128;
    const int mb = (w & 1) * 64, nb = (w >> 1) * 64;
    const int fr = lane & 15, fq = lane >> 4;

    f32x4 acc[16];
#pragma unroll
    for (int i = 0; i < 16; i++) acc[i] = (f32x4){0.f, 0.f, 0.f, 0.f};

    const int brow = lane >> 2, bk = lane & 3;
    const int klog = bk ^ ((brow >> 1) & 3);
    const int arow = lane >> 3, ag = lane & 7;

    for (int k0 = 0; k0 < K; k0 += 32) {
        __syncthreads();
        if constexpr (sizeof(AT) == 4) {
#pragma unroll
            for (int i = 0; i < 4; i++) {
                const int grp = w * 4 + i;
                const int row = grp * 8 + arow;
                const int gl = ag ^ (row & 7);
                dma16((const float*)A + (size_t)(bm + row) * K + k0 + gl * 4,
                      AsRaw + grp * 1024);
            }
        } else {
#pragma unroll
            for (int i = 0; i < 2; i++) {
                const int grp = w * 2 + i;
                const int row = grp * 16 + brow;
                dma16((const ushort_t*)A + (size_t)(bm + row) * K + k0 + klog * 8,
                      (ushort_t*)AsRaw + grp * 512);
            }
        }
#pragma unroll
        for (int i = 0; i < 2; i++) {
            const int grp = w * 2 + i;
            const int row = grp * 16 + brow;
            dma16(Bt + (size_t)(bn + row) * K + k0 + klog * 8, Bs + grp * 512);
        }
        __syncthreads();

        short8 af[4], bf[4];
        if constexpr (sizeof(AT) == 4) {
#pragma unroll
            for (int i = 0; i < 4; i++) {
                const int row = mb + i * 16 + fr;
                const float* base = (const float*)AsRaw + row * 32;
                const f32x4 p0 = *(const f32x4*)(base + (((2 * fq)     ^ (fr & 7)) * 4));
                const f32x4 p1 = *(const f32x4*)(base + (((2 * fq + 1) ^ (fr & 7)) * 4));
                unsigned rr[4] = { pk2bf(p0.x, p0.y), pk2bf(p0.z, p0.w),
                                   pk2bf(p1.x, p1.y), pk2bf(p1.z, p1.w) };
                af[i] = *(short8*)rr;
            }
        } else {
#pragma unroll
            for (int i = 0; i < 4; i++) {
                const int row = mb + i * 16 + fr;
                af[i] = *(const short8*)((const ushort_t*)AsRaw + row * 32 + (fq ^ ((fr >> 1) & 3)) * 8);
            }
        }
#pragma unroll
        for (int j = 0; j < 4; j++) {
            const int row = nb + j * 16 + fr;
            bf[j] = *(const short8*)(Bs + row * 32 + (fq ^ ((fr >> 1) & 3)) * 8);
        }
#pragma unroll
        for (int i = 0; i < 4; i++)
#pragma unroll
            for (int j = 0; j < 4; j++)
                acc[i * 4 + j] = __builtin_amdgcn_mfma_f32_16x16x32_bf16(
                    af[i], bf[j], acc[i * 4 + j], 0, 0, 0);
    }

#pragma unroll
    for (int j = 0; j < 4; j++) {
        const int n = bn + nb + j * 16 + fr;
        const float bv = (n < Nb) ? bias[n] : 0.f;
#pragma unroll
        for (int i = 0; i < 4; i++) {
            const f32x4 a = acc[i * 4 + j];
#pragma unroll
            for (int r = 0; r < 4; r++) {
                const int m = bm + mb + i * 16 + fq * 4 + r;
                float v = a[r] + bv;
                if (RELU) v = fmaxf(v, 0.f);
                C[((size_t)m * row_mul + row_add) * (size_t)N + n] = f2bf(v);
            }
        }
    }
}

// ---------- fc1 GEMM with fused T-mean epilogue (r3-proven) ----------
__global__ __launch_bounds__(256)
void gemm_fc1_mean(const ushort_t* __restrict__ A, const ushort_t* __restrict__ Bt,
                   const float* __restrict__ bias, float* __restrict__ cmean)
{
    __shared__ __align__(16) ushort_t AsS[128 * 32];
    __shared__ __align__(16) ushort_t Bs[128 * 32];
    const int t = threadIdx.x;
    const int lane = t & 63, w = t >> 6;
    const int bm = blockIdx.y * 128, bn = blockIdx.x * 128;
    const int mb = (w & 1) * 64, nb = (w >> 1) * 64;
    const int fr = lane & 15, fq = lane >> 4;
    const int K = 512;

    f32x4 acc[16];
#pragma unroll
    for (int i = 0; i < 16; i++) acc[i] = (f32x4){0.f, 0.f, 0.f, 0.f};

    const int brow = lane >> 2, bk = lane & 3;
    const int klog = bk ^ ((brow >> 1) & 3);

    for (int k0 = 0; k0 < K; k0 += 32) {
        __syncthreads();
#pragma unroll
        for (int i = 0; i < 2; i++) {
            const int grp = w * 2 + i;
            const int row = grp * 16 + brow;
            dma16(A + (size_t)(bm + row) * K + k0 + klog * 8, AsS + grp * 512);
        }
#pragma unroll
        for (int i = 0; i < 2; i++) {
            const int grp = w * 2 + i;
            const int row = grp * 16 + brow;
            dma16(Bt + (size_t)(bn + row) * K + k0 + klog * 8, Bs + grp * 512);
        }
        __syncthreads();

        short8 af[4], bf[4];
#pragma unroll
        for (int i = 0; i < 4; i++) {
            const int row = mb + i * 16 + fr;
            af[i] = *(const short8*)(AsS + row * 32 + (fq ^ ((fr >> 1) & 3)) * 8);
        }
#pragma unroll
        for (int j = 0; j < 4; j++) {
            const int row = nb + j * 16 + fr;
            bf[j] = *(const short8*)(Bs + row * 32 + (fq ^ ((fr >> 1) & 3)) * 8);
        }
#pragma unroll
        for (int i = 0; i < 4; i++)
#pragma unroll
            for (int j = 0; j < 4; j++)
                acc[i * 4 + j] = __builtin_amdgcn_mfma_f32_16x16x32_bf16(
                    af[i], bf[j], acc[i * 4 + j], 0, 0, 0);
    }

    const int nidx = (bm + mb) >> 6;
#pragma unroll
    for (int j = 0; j < 4; j++) {
        const int n = bn + nb + j * 16 + fr;
        const float bv = bias[n];
        float s = 0.f;
#pragma unroll
        for (int i = 0; i < 4; i++) {
            const f32x4 a = acc[i * 4 + j];
#pragma unroll
            for (int r = 0; r < 4; r++) s += fmaxf(a[r] + bv, 0.f);
        }
        s += __shfl_xor(s, 16);
        s += __shfl_xor(s, 32);
        if (fq == 0) cmean[(size_t)nidx * 1024 + n] = s * (1.0f / 64.0f);
    }
}

// ---------- graph stage v2: 4 waves per graph, wave-parallel reductions ----------
// r4 change: grid had only 8 waves/CU (1 wave/graph) => latency-starved
// (MfmaUtil 1.9%, VALUBusy 13%, occ 20%). Now 256 thr/block: phase A splits the
// 5 MFMA chains + obj-mean across 4 waves; serial lane<16 phases become 16x16
// thread maps with shfl_xor tree reductions; final 32x512 GEMV splits by cols.
__global__ __launch_bounds__(256)
void graph_mfma(const ushort_t* __restrict__ obj,
                const ushort_t* __restrict__ W1t, const float* __restrict__ b1,
                const ushort_t* __restrict__ W2b, const float* __restrict__ b2,
                const ushort_t* __restrict__ W3t, const float* __restrict__ b3,
                const ushort_t* __restrict__ W4b, const float* __restrict__ b4,
                ushort_t* __restrict__ cbuf)
{
    __shared__ float ssb[16 * 17];
    __shared__ float adjt[16 * 20];
    __shared__ float t1s[16 * 36];
    __shared__ float t3s[16 * 36];
    __shared__ float x1s[16 * 36];
    __shared__ float y2s[16 * 36];
    __shared__ float y22s[16 * 17];
    __shared__ float a3t[16 * 20];
    __shared__ __align__(16) float oms[512];
    __shared__ float dv[16], dv3[16], nrm[16], cA[16], cA3[16];
    __shared__ float zc1[32], zc4[32];

    const int t = threadIdx.x;
    const int w = t >> 6, lane = t & 63;
    const int r = lane & 15, fq = lane >> 4;
    const ushort_t* xg = obj + (size_t)blockIdx.x * 8192;

    // ---- phase A: wave-split heavy lifting ----
    if (w == 0) {
        // S = x @ x^T
        f32x4 sacc = (f32x4){0.f, 0.f, 0.f, 0.f};
#pragma unroll 8
        for (int kk = 0; kk < 16; kk++) {
            const short8 xk = *(const short8*)(xg + r * 512 + kk * 32 + fq * 8);
            sacc = __builtin_amdgcn_mfma_f32_16x16x32_bf16(xk, xk, sacc, 0, 0, 0);
        }
#pragma unroll
        for (int i = 0; i < 4; i++) ssb[(fq * 4 + i) * 17 + r] = sacc[i];
    } else if (w == 1) {
        // t1 = x @ W1 (32 cols)
        f32x4 a10 = (f32x4){0.f,0.f,0.f,0.f}, a11 = a10;
#pragma unroll 4
        for (int kk = 0; kk < 16; kk++) {
            const short8 xk  = *(const short8*)(xg + r * 512 + kk * 32 + fq * 8);
            const short8 w10 = *(const short8*)(W1t + (size_t)(r)      * 512 + kk * 32 + fq * 8);
            const short8 w11 = *(const short8*)(W1t + (size_t)(16 + r) * 512 + kk * 32 + fq * 8);
            a10 = __builtin_amdgcn_mfma_f32_16x16x32_bf16(xk, w10, a10, 0, 0, 0);
            a11 = __builtin_amdgcn_mfma_f32_16x16x32_bf16(xk, w11, a11, 0, 0, 0);
        }
#pragma unroll
        for (int i = 0; i < 4; i++) {
            const int m = fq * 4 + i;
            t1s[m * 36 + r]      = a10[i];
            t1s[m * 36 + 16 + r] = a11[i];
        }
    } else if (w == 2) {
        // t3 = x @ W3 (32 cols)
        f32x4 a30 = (f32x4){0.f,0.f,0.f,0.f}, a31 = a30;
#pragma unroll 4
        for (int kk = 0; kk < 16; kk++) {
            const short8 xk  = *(const short8*)(xg + r * 512 + kk * 32 + fq * 8);
            const short8 w30 = *(const short8*)(W3t + (size_t)(r)      * 512 + kk * 32 + fq * 8);
            const short8 w31 = *(const short8*)(W3t + (size_t)(16 + r) * 512 + kk * 32 + fq * 8);
            a30 = __builtin_amdgcn_mfma_f32_16x16x32_bf16(xk, w30, a30, 0, 0, 0);
            a31 = __builtin_amdgcn_mfma_f32_16x16x32_bf16(xk, w31, a31, 0, 0, 0);
        }
#pragma unroll
        for (int i = 0; i < 4; i++) {
            const int m = fq * 4 + i;
            t3s[m * 36 + r]      = a30[i];
            t3s[m * 36 + 16 + r] = a31[i];
        }
    } else {
        // obj column sums (the "o" mean): om[c] = sum over 16 rows
        float om[8] = {0,0,0,0,0,0,0,0};
#pragma unroll
        for (int m = 0; m < 16; m++) {
            const uint4 q = *(const uint4*)(xg + m * 512 + lane * 8);
            om[0] += bflo(q.x); om[1] += bfhi(q.x);
            om[2] += bflo(q.y); om[3] += bfhi(q.y);
            om[4] += bflo(q.z); om[5] += bfhi(q.z);
            om[6] += bflo(q.w); om[7] += bfhi(q.w);
        }
        *(float4*)&oms[lane * 8]     = (float4){om[0], om[1], om[2], om[3]};
        *(float4*)&oms[lane * 8 + 4] = (float4){om[4], om[5], om[6], om[7]};
    }
    __syncthreads();

    // ---- P1: row softmax (16 rows x 16-lane groups, tree reduce) ----
    {
        const int row = t >> 4, col = t & 15;
        const float v = ssb[row * 17 + col];
        float mx = v;
        mx = fmaxf(mx, __shfl_xor(mx, 1));
        mx = fmaxf(mx, __shfl_xor(mx, 2));
        mx = fmaxf(mx, __shfl_xor(mx, 4));
        mx = fmaxf(mx, __shfl_xor(mx, 8));
        const float e = expf(v - mx);
        float s = e;
        s += __shfl_xor(s, 1); s += __shfl_xor(s, 2);
        s += __shfl_xor(s, 4); s += __shfl_xor(s, 8);
        ssb[row * 17 + col] = e;
        if (col == 0) dv[row] = rsqrtf(s);
    }
    __syncthreads();

    // ---- P2: adjt = normalized adj (transposed) + fused col-degree cA ----
    {
        const int j = t >> 4, rr = t & 15;
        const float av = ssb[rr * 17 + j] * dv[rr] * dv[j];
        adjt[j * 20 + rr] = av;
        float s = av;
        s += __shfl_xor(s, 1); s += __shfl_xor(s, 2);
        s += __shfl_xor(s, 4); s += __shfl_xor(s, 8);
        if (rr == 0) cA[j] = s;
    }
    __syncthreads();

    // ---- P3: x1 = relu(adj@t1 + b1), y2 = relu(adj@t3 + b3); 2 rows/thread ----
    {
        const int c = t & 31, g = t >> 5;
        const int m0 = g * 2, m1 = m0 + 1;
        const float bb1 = b1[c], bb3 = b3[c];
        float ax0 = bb1, ax1 = bb1, ay0 = bb3, ay1 = bb3;
#pragma unroll
        for (int j = 0; j < 16; j++) {
            const float t1v = t1s[j * 36 + c], t3v = t3s[j * 36 + c];
            const float a0 = adjt[j * 20 + m0], a1 = adjt[j * 20 + m1];
            ax0 = fmaf(a0, t1v, ax0); ax1 = fmaf(a1, t1v, ax1);
            ay0 = fmaf(a0, t3v, ay0); ay1 = fmaf(a1, t3v, ay1);
        }
        x1s[m0 * 36 + c] = fmaxf(ax0, 0.f); x1s[m1 * 36 + c] = fmaxf(ax1, 0.f);
        y2s[m0 * 36 + c] = fmaxf(ay0, 0.f); y2s[m1 * 36 + c] = fmaxf(ay1, 0.f);
    }
    __syncthreads();

    // ---- P4: y22 = y2@y2^T (one el/thread) + fused row-norm ----
    {
        const int i2 = t >> 4, j2 = t & 15;
        float s = 0.f;
#pragma unroll
        for (int k4 = 0; k4 < 8; k4++) {
            const float4 yi = *(const float4*)&y2s[i2 * 36 + k4 * 4];
            const float4 yj = *(const float4*)&y2s[j2 * 36 + k4 * 4];
            s = fmaf(yi.x, yj.x, s); s = fmaf(yi.y, yj.y, s);
            s = fmaf(yi.z, yj.z, s); s = fmaf(yi.w, yj.w, s);
        }
        y22s[i2 * 17 + j2] = s;
        float sq = s * s;
        sq += __shfl_xor(sq, 1); sq += __shfl_xor(sq, 2);
        sq += __shfl_xor(sq, 4); sq += __shfl_xor(sq, 8);
        if (j2 == 0) nrm[i2] = sqrtf(sq);
    }
    __syncthreads();

    // ---- P5: adj3 (transposed) + fused degree dv3 ----
    {
        const int j = t >> 4, rr = t & 15;
        const float av = 1.0f + y22s[rr * 17 + j] / (nrm[rr] * nrm[j]);
        a3t[j * 20 + rr] = av;
        float s = av;
        s += __shfl_xor(s, 1); s += __shfl_xor(s, 2);
        s += __shfl_xor(s, 4); s += __shfl_xor(s, 8);
        if (rr == 0) dv3[j] = rsqrtf(s);
    }
    __syncthreads();

    // ---- P6: cA3[a] = (sum_b a3t[a][b]*dv3[b]) * dv3[a] ----
    {
        const int a = t >> 4, b = t & 15;
        float s = a3t[a * 20 + b] * dv3[b];
        s += __shfl_xor(s, 1); s += __shfl_xor(s, 2);
        s += __shfl_xor(s, 4); s += __shfl_xor(s, 8);
        if (b == 0) cA3[a] = s * dv3[a];
    }
    __syncthreads();

    // ---- P7: zc1/zc4 column contractions (32 cols, cheap) ----
    if (t < 32) {
        float s1 = 0.f, s4 = 0.f;
#pragma unroll
        for (int j = 0; j < 16; j++) {
            s1 = fmaf(cA[j],  x1s[j * 36 + t], s1);
            s4 = fmaf(cA3[j], y2s[j * 36 + t], s4);
        }
        zc1[t] = s1; zc4[t] = s4;
    }
    __syncthreads();

    // ---- P8: final 32x512 GEMV + combine, split by columns across waves ----
    {
        const int c0 = w * 128 + lane * 2;
        float gm0 = 0.f, gm1 = 0.f;
#pragma unroll 8
        for (int k = 0; k < 32; k++) {
            const float z1 = zc1[k], z4 = zc4[k];
            const unsigned u2 = *(const unsigned*)(W2b + (size_t)k * 512 + c0);
            const unsigned u4 = *(const unsigned*)(W4b + (size_t)k * 512 + c0);
            gm0 = fmaf(z1, bflo(u2), gm0); gm0 = fmaf(z4, bflo(u4), gm0);
            gm1 = fmaf(z1, bfhi(u2), gm1); gm1 = fmaf(z4, bfhi(u4), gm1);
        }
        const float bs0 = b2[c0] + b4[c0];
        const float bs1 = b2[c0 + 1] + b4[c0 + 1];
        const float gmean0 = 0.5f * bs0 + gm0 * (1.0f / 32.0f);
        const float gmean1 = 0.5f * bs1 + gm1 * (1.0f / 32.0f);
        const float f0 = 0.5f * (oms[c0]     * 0.0625f + gmean0);
        const float f1 = 0.5f * (oms[c0 + 1] * 0.0625f + gmean1);
        *(unsigned*)(cbuf + (size_t)blockIdx.x * 512 + c0) =
            pk2bf(fmaxf(f0, 0.f), fmaxf(f1, 0.f));
    }
}

// ---------- clf GEMV on transposed W: contiguous 4KB row reads ----------
__global__ __launch_bounds__(256)
void clf_col(const float* __restrict__ cmean, const float* __restrict__ Wt,
             const float* __restrict__ clf_b, float* __restrict__ out)
{
    __shared__ float red[8][33];
    const int j = blockIdx.x;            // 0..499
    const int t = threadIdx.x;
    const int n = t & 31, kp = t >> 5;   // 8 k-parts x 128
    const float* cm = cmean + (size_t)n * 1024 + kp * 128;
    const float* wp = Wt + (size_t)j * 1024 + kp * 128;
    float acc = 0.f;
#pragma unroll
    for (int k = 0; k < 128; k += 4) {
        const float4 c = *(const float4*)(cm + k);
        const float4 wv = *(const float4*)(wp + k);
        acc = fmaf(c.x, wv.x, acc);
        acc = fmaf(c.y, wv.y, acc);
        acc = fmaf(c.z, wv.z, acc);
        acc = fmaf(c.w, wv.w, acc);
    }
    red[kp][n] = acc;
    __syncthreads();
    if (t < 32) {
        float s = red[0][t];
#pragma unroll
        for (int p = 1; p < 8; p++) s += red[p][t];
        out[(size_t)t * 500 + j] = s + clf_b[j];
    }
}

// ---------- launcher ----------
extern "C" void kernel_launch(void* const* d_in, const int* in_sizes, int n_in,
                              void* d_out, int out_size, void* d_ws, size_t ws_size,
                              hipStream_t stream)
{
    const float* object_raw = (const float*)d_in[0];
    const float* action_raw = (const float*)d_in[1];
    const float* W_obj = (const float*)d_in[2];
    const float* b_obj = (const float*)d_in[3];
    const float* W_act = (const float*)d_in[4];
    const float* b_act = (const float*)d_in[5];
    const float* gc1_W = (const float*)d_in[6];
    const float* gc1_b = (const float*)d_in[7];
    const float* gc2_W = (const float*)d_in[8];
    const float* gc2_b = (const float*)d_in[9];
    const float* gc3_W = (const float*)d_in[10];
    const float* gc3_b = (const float*)d_in[11];
    const float* gc4_W = (const float*)d_in[12];
    const float* gc4_b = (const float*)d_in[13];
    const float* fc1_W = (const float*)d_in[14];
    const float* fc1_b = (const float*)d_in[15];
    const float* clf_W = (const float*)d_in[16];
    const float* clf_b = (const float*)d_in[17];

    char* ws = (char*)d_ws;
    const size_t MB = 1024 * 1024;
    ushort_t* obj_bf = (ushort_t*)(ws);                       // 32 MB
    ushort_t* cbuf   = (ushort_t*)(ws + 32 * MB);             // 2 MB
    float*    WclfT  = (float*)   (ws + 34 * MB);             // 2 MB (500x1024 fp32)
    float*    cmean  = (float*)   (ws + 38 * MB);             // 128 KB
    ushort_t* WobjT  = (ushort_t*)(ws + 39 * MB);             // 512 KB
    ushort_t* WactT  = (ushort_t*)(ws + 39 * MB + 512 * 1024);
    ushort_t* fc1T   = (ushort_t*)(ws + 40 * MB);             // 1 MB
    ushort_t* W1t    = (ushort_t*)(ws + 41 * MB);
    ushort_t* W3t    = (ushort_t*)(ws + 41 * MB + 32 * 1024);
    ushort_t* W2bf   = (ushort_t*)(ws + 41 * MB + 64 * 1024);
    ushort_t* W4bf   = (ushort_t*)(ws + 41 * MB + 96 * 1024);

    // 1. weight prep (also transposes clf_W to fp32 WclfT)
    prep_weights<<<dim3(1584), 256, 0, stream>>>(
        W_obj, WobjT, W_act, WactT, fc1_W, fc1T,
        gc1_W, W1t, gc3_W, W3t, gc2_W, W2bf, gc4_W, W4bf,
        clf_W, WclfT);

    // 2. obj GEMM: 128-row tile, 1 block/CU, transaction-minimized
    gemm_obj_stream<<<dim3(256), 512, 0, stream>>>(object_raw, WobjT, b_obj, obj_bf);

    // 3. act GEMM writes rows g*16+8
    gemm_dma<1, float><<<dim3(4, 16), 256, 0, stream>>>(
        action_raw, WactT, b_act, obj_bf, 512, 512, 512, 16, 8);

    // 4. graph stage: 4 waves per graph (32 waves/CU capacity)
    graph_mfma<<<dim3(2048), 256, 0, stream>>>(
        obj_bf, W1t, gc1_b, W2bf, gc2_b, W3t, gc3_b, W4bf, gc4_b, cbuf);

    // 5. cmean = mean_T(relu(cbuf @ fc1_W + fc1_b))  -- mean fused into epilogue
    gemm_fc1_mean<<<dim3(8, 16), 256, 0, stream>>>(cbuf, fc1T, fc1_b, cmean);

    // 6. out = cmean @ clf_W + clf_b (transposed W, contiguous reads)
    clf_col<<<dim3(500), 256, 0, stream>>>(cmean, WclfT, clf_b, (float*)d_out);
}

// Round 5
// 229.972 us; speedup vs baseline: 1.0274x; 1.0274x over previous
//
#include <hip/hip_runtime.h>
#include <hip/hip_bf16.h>

using ushort_t = unsigned short;
using f32x4  = __attribute__((ext_vector_type(4))) float;
using short8 = __attribute__((ext_vector_type(8))) short;

// ---------- bf16 helpers ----------
__device__ __forceinline__ float bflo(unsigned p) {
    union { unsigned u; float f; } x; x.u = p << 16; return x.f;
}
__device__ __forceinline__ float bfhi(unsigned p) {
    union { unsigned u; float f; } x; x.u = p & 0xffff0000u; return x.f;
}
__device__ __forceinline__ ushort_t f2bf(float f) {
    __hip_bfloat16 h = __float2bfloat16(f);   // RTNE
    return *(ushort_t*)&h;
}
__device__ __forceinline__ unsigned pk2bf(float lo, float hi) {
    __hip_bfloat162 h = __float22bfloat162_rn({lo, hi});  // RTNE, packed
    return *(unsigned*)&h;
}

// ---------- combined weight prep ----------
__device__ __forceinline__ void tr_tile(const float* __restrict__ S, ushort_t* __restrict__ D,
                                        int K, int N, int Npad, int bx, int by,
                                        int tx, int ty, float* tile /*32*33*/)
{
    const int k0 = by * 32, n0 = bx * 32;
#pragma unroll
    for (int r = 0; r < 4; r++) {
        const int k = k0 + ty + r * 8, n = n0 + tx;
        tile[(ty + r * 8) * 33 + tx] = (k < K && n < N) ? S[(size_t)k * N + n] : 0.f;
    }
    __syncthreads();
#pragma unroll
    for (int r = 0; r < 4; r++) {
        const int n = n0 + ty + r * 8, k = k0 + tx;
        if (n < Npad && k < K) D[(size_t)n * K + k] = f2bf(tile[tx * 33 + ty + r * 8]);
    }
}

// fp32 -> fp32 transpose (for clf_W)
__device__ __forceinline__ void trf_tile(const float* __restrict__ S, float* __restrict__ D,
                                         int K, int N, int bx, int by,
                                         int tx, int ty, float* tile /*32*33*/)
{
    const int k0 = by * 32, n0 = bx * 32;
#pragma unroll
    for (int r = 0; r < 4; r++) {
        const int k = k0 + ty + r * 8, n = n0 + tx;
        tile[(ty + r * 8) * 33 + tx] = (k < K && n < N) ? S[(size_t)k * N + n] : 0.f;
    }
    __syncthreads();
#pragma unroll
    for (int r = 0; r < 4; r++) {
        const int n = n0 + ty + r * 8, k = k0 + tx;
        if (n < N && k < K) D[(size_t)n * K + k] = tile[tx * 33 + ty + r * 8];
    }
}

__global__ __launch_bounds__(256)
void prep_weights(const float* __restrict__ Wobj, ushort_t* __restrict__ WobjT,
                  const float* __restrict__ Wact, ushort_t* __restrict__ WactT,
                  const float* __restrict__ fc1W, ushort_t* __restrict__ fc1T,
                  const float* __restrict__ gc1W, ushort_t* __restrict__ W1t,
                  const float* __restrict__ gc3W, ushort_t* __restrict__ W3t,
                  const float* __restrict__ gc2W, ushort_t* __restrict__ W2bf,
                  const float* __restrict__ gc4W, ushort_t* __restrict__ W4bf,
                  const float* __restrict__ clfW, float* __restrict__ WclfT)
{
    __shared__ float tile[32 * 33];
    const int b = blockIdx.x;
    const int t = threadIdx.x;
    const int tx = t & 31, ty = t >> 5;

    if (b < 1056) {
        const float* S; ushort_t* D; int K, N, Npad, nt, l;
        if      (b < 256)  { S = Wobj; D = WobjT; K = 512; N = 512;  Npad = 512;  nt = 16; l = b; }
        else if (b < 512)  { S = Wact; D = WactT; K = 512; N = 512;  Npad = 512;  nt = 16; l = b - 256; }
        else if (b < 1024) { S = fc1W; D = fc1T;  K = 512; N = 1024; Npad = 1024; nt = 32; l = b - 512; }
        else if (b < 1040) { S = gc1W; D = W1t;   K = 512; N = 32;   Npad = 32;   nt = 1;  l = b - 1024; }
        else               { S = gc3W; D = W3t;   K = 512; N = 32;   Npad = 32;   nt = 1;  l = b - 1040; }
        tr_tile(S, D, K, N, Npad, l % nt, l / nt, tx, ty, tile);
    } else if (b < 1072) {
        const float* S = (b < 1064) ? gc2W : gc4W;
        ushort_t* D    = (b < 1064) ? W2bf : W4bf;
        const int i = (b < 1064 ? b - 1056 : b - 1064) * 256 + t;
        const float4 x = ((const float4*)S)[2 * i];
        const float4 y = ((const float4*)S)[2 * i + 1];
        unsigned r[4] = { pk2bf(x.x, x.y), pk2bf(x.z, x.w), pk2bf(y.x, y.y), pk2bf(y.z, y.w) };
        ((uint4*)D)[i] = *(uint4*)r;
    } else {
        const int l = b - 1072;
        trf_tile(clfW, WclfT, 1024, 500, l & 15, l >> 4, tx, ty, tile);
    }
}

// ---------- obj GEMM v3 (r2-proven) ----------
__global__ __launch_bounds__(512, 2)
void gemm_obj_stream(const float* __restrict__ A, const ushort_t* __restrict__ Bt,
                     const float* __restrict__ bias, ushort_t* __restrict__ C)
{
    __shared__ __align__(16) ushort_t As[128 * 512];
    const int t = threadIdx.x;
    const int lane = t & 63, w = t >> 6;
    const int bm = blockIdx.x * 128;
    const int fr = lane & 15, fq = lane >> 4;

    const float4* A4 = (const float4*)(A + (size_t)bm * 512);
#pragma unroll
    for (int i = 0; i < 16; i++) {
        const int fl = i * 1024 + t * 2;
        const int row = fl >> 7;
        const float4 p0 = A4[fl];
        const float4 p1 = A4[fl + 1];
        unsigned rr[4] = { pk2bf(p0.x, p0.y), pk2bf(p0.z, p0.w),
                           pk2bf(p1.x, p1.y), pk2bf(p1.z, p1.w) };
        *(uint4*)&As[row * 512 + ((lane ^ (row & 7)) * 8)] = *(uint4*)rr;
    }

    const int nw = w * 64;
    const ushort_t* Bbase = Bt + (size_t)(nw + fr) * 512 + fq * 8;

    uint4 bA[4], bB[4];
#pragma unroll
    for (int j = 0; j < 4; j++) bA[j] = *(const uint4*)(Bbase + (size_t)j * 16 * 512);

    __syncthreads();

    f32x4 acc[4][8];
#pragma unroll
    for (int j = 0; j < 4; j++)
#pragma unroll
        for (int i = 0; i < 8; i++) acc[j][i] = (f32x4){0.f, 0.f, 0.f, 0.f};

    for (int kk = 0; kk < 16; kk += 2) {
        short8 af[8];
#pragma unroll
        for (int i = 0; i < 8; i++)
            af[i] = *(const short8*)&As[(i * 16 + fr) * 512 + (((kk * 4 + fq) ^ (fr & 7)) * 8)];
#pragma unroll
        for (int j = 0; j < 4; j++) {
            bB[j] = *(const uint4*)(Bbase + (size_t)j * 16 * 512 + (kk + 1) * 32);
            const short8 bf = *(const short8*)&bA[j];
#pragma unroll
            for (int i = 0; i < 8; i++)
                acc[j][i] = __builtin_amdgcn_mfma_f32_16x16x32_bf16(af[i], bf, acc[j][i], 0, 0, 0);
        }
#pragma unroll
        for (int i = 0; i < 8; i++)
            af[i] = *(const short8*)&As[(i * 16 + fr) * 512 + ((((kk + 1) * 4 + fq) ^ (fr & 7)) * 8)];
#pragma unroll
        for (int j = 0; j < 4; j++) {
            if (kk + 2 < 16)
                bA[j] = *(const uint4*)(Bbase + (size_t)j * 16 * 512 + (kk + 2) * 32);
            const short8 bf = *(const short8*)&bB[j];
#pragma unroll
            for (int i = 0; i < 8; i++)
                acc[j][i] = __builtin_amdgcn_mfma_f32_16x16x32_bf16(af[i], bf, acc[j][i], 0, 0, 0);
        }
    }

    __syncthreads();
#pragma unroll
    for (int j = 0; j < 4; j++) {
        const int col0 = j * 16 + fr;
        const float bv = bias[nw + col0];
#pragma unroll
        for (int i = 0; i < 8; i++) {
#pragma unroll
            for (int rr2 = 0; rr2 < 4; rr2++) {
                const int m = i * 16 + fq * 4 + rr2;
                const int pc = col0 ^ (((m >> 2) & 3) << 4);
                As[m * 512 + nw + pc] = f2bf(fmaxf(acc[j][i][rr2] + bv, 0.f));
            }
        }
    }
    __syncthreads();
#pragma unroll
    for (int i2 = 0; i2 < 16; i2++) {
        const int fl = i2 * 512 + t;
        const int m  = fl >> 6;
        const int n0 = (fl & 63) * 8;
        const int sl = n0 & ~63;
        const int cl = n0 & 63;
        const uint4 v = *(const uint4*)&As[m * 512 + sl + (cl ^ (((m >> 2) & 3) << 4))];
        *(uint4*)&C[(size_t)(bm + m) * 512 + n0] = v;
    }
}

// ---------- generic MFMA GEMM (proven for act) ----------
typedef __attribute__((address_space(1))) void glb_void;
typedef __attribute__((address_space(3))) void lds_void;
__device__ __forceinline__ void dma16(const void* g, void* l) {
    __builtin_amdgcn_global_load_lds((glb_void*)(unsigned long long)(uintptr_t)g,
                                     (lds_void*)(unsigned)(uintptr_t)l, 16, 0, 0);
}

template<int RELU, typename AT>
__global__ __launch_bounds__(256)
void gemm_dma(const AT* __restrict__ A, const ushort_t* __restrict__ Bt,
              const float* __restrict__ bias, ushort_t* __restrict__ C,
              int N, int K, int Nb, int row_mul, int row_add)
{
    __shared__ __align__(16) char     AsRaw[128 * 32 * sizeof(AT)];
    __shared__ __align__(16) ushort_t Bs[128 * 32];
    const int t = threadIdx.x;
    const int lane = t & 63, w = t >> 6;
    const int bm = blockIdx.y * 128, bn = blockIdx.x * 128;
    const int mb = (w & 1) * 64, nb = (w >> 1) * 64;
    const int fr = lane & 15, fq = lane >> 4;

    f32x4 acc[16];
#pragma unroll
    for (int i = 0; i < 16; i++) acc[i] = (f32x4){0.f, 0.f, 0.f, 0.f};

    const int brow = lane >> 2, bk = lane & 3;
    const int klog = bk ^ ((brow >> 1) & 3);
    const int arow = lane >> 3, ag = lane & 7;

    for (int k0 = 0; k0 < K; k0 += 32) {
        __syncthreads();
        if constexpr (sizeof(AT) == 4) {
#pragma unroll
            for (int i = 0; i < 4; i++) {
                const int grp = w * 4 + i;
                const int row = grp * 8 + arow;
                const int gl = ag ^ (row & 7);
                dma16((const float*)A + (size_t)(bm + row) * K + k0 + gl * 4,
                      AsRaw + grp * 1024);
            }
        } else {
#pragma unroll
            for (int i = 0; i < 2; i++) {
                const int grp = w * 2 + i;
                const int row = grp * 16 + brow;
                dma16((const ushort_t*)A + (size_t)(bm + row) * K + k0 + klog * 8,
                      (ushort_t*)AsRaw + grp * 512);
            }
        }
#pragma unroll
        for (int i = 0; i < 2; i++) {
            const int grp = w * 2 + i;
            const int row = grp * 16 + brow;
            dma16(Bt + (size_t)(bn + row) * K + k0 + klog * 8, Bs + grp * 512);
        }
        __syncthreads();

        short8 af[4], bf[4];
        if constexpr (sizeof(AT) == 4) {
#pragma unroll
            for (int i = 0; i < 4; i++) {
                const int row = mb + i * 16 + fr;
                const float* base = (const float*)AsRaw + row * 32;
                const f32x4 p0 = *(const f32x4*)(base + (((2 * fq)     ^ (fr & 7)) * 4));
                const f32x4 p1 = *(const f32x4*)(base + (((2 * fq + 1) ^ (fr & 7)) * 4));
                unsigned rr[4] = { pk2bf(p0.x, p0.y), pk2bf(p0.z, p0.w),
                                   pk2bf(p1.x, p1.y), pk2bf(p1.z, p1.w) };
                af[i] = *(short8*)rr;
            }
        } else {
#pragma unroll
            for (int i = 0; i < 4; i++) {
                const int row = mb + i * 16 + fr;
                af[i] = *(const short8*)((const ushort_t*)AsRaw + row * 32 + (fq ^ ((fr >> 1) & 3)) * 8);
            }
        }
#pragma unroll
        for (int j = 0; j < 4; j++) {
            const int row = nb + j * 16 + fr;
            bf[j] = *(const short8*)(Bs + row * 32 + (fq ^ ((fr >> 1) & 3)) * 8);
        }
#pragma unroll
        for (int i = 0; i < 4; i++)
#pragma unroll
            for (int j = 0; j < 4; j++)
                acc[i * 4 + j] = __builtin_amdgcn_mfma_f32_16x16x32_bf16(
                    af[i], bf[j], acc[i * 4 + j], 0, 0, 0);
    }

#pragma unroll
    for (int j = 0; j < 4; j++) {
        const int n = bn + nb + j * 16 + fr;
        const float bv = (n < Nb) ? bias[n] : 0.f;
#pragma unroll
        for (int i = 0; i < 4; i++) {
            const f32x4 a = acc[i * 4 + j];
#pragma unroll
            for (int r = 0; r < 4; r++) {
                const int m = bm + mb + i * 16 + fq * 4 + r;
                float v = a[r] + bv;
                if (RELU) v = fmaxf(v, 0.f);
                C[((size_t)m * row_mul + row_add) * (size_t)N + n] = f2bf(v);
            }
        }
    }
}

// ---------- fc1 GEMM with fused T-mean epilogue (r3-proven) ----------
__global__ __launch_bounds__(256)
void gemm_fc1_mean(const ushort_t* __restrict__ A, const ushort_t* __restrict__ Bt,
                   const float* __restrict__ bias, float* __restrict__ cmean)
{
    __shared__ __align__(16) ushort_t AsS[128 * 32];
    __shared__ __align__(16) ushort_t Bs[128 * 32];
    const int t = threadIdx.x;
    const int lane = t & 63, w = t >> 6;
    const int bm = blockIdx.y * 128, bn = blockIdx.x * 128;
    const int mb = (w & 1) * 64, nb = (w >> 1) * 64;
    const int fr = lane & 15, fq = lane >> 4;
    const int K = 512;

    f32x4 acc[16];
#pragma unroll
    for (int i = 0; i < 16; i++) acc[i] = (f32x4){0.f, 0.f, 0.f, 0.f};

    const int brow = lane >> 2, bk = lane & 3;
    const int klog = bk ^ ((brow >> 1) & 3);

    for (int k0 = 0; k0 < K; k0 += 32) {
        __syncthreads();
#pragma unroll
        for (int i = 0; i < 2; i++) {
            const int grp = w * 2 + i;
            const int row = grp * 16 + brow;
            dma16(A + (size_t)(bm + row) * K + k0 + klog * 8, AsS + grp * 512);
        }
#pragma unroll
        for (int i = 0; i < 2; i++) {
            const int grp = w * 2 + i;
            const int row = grp * 16 + brow;
            dma16(Bt + (size_t)(bn + row) * K + k0 + klog * 8, Bs + grp * 512);
        }
        __syncthreads();

        short8 af[4], bf[4];
#pragma unroll
        for (int i = 0; i < 4; i++) {
            const int row = mb + i * 16 + fr;
            af[i] = *(const short8*)(AsS + row * 32 + (fq ^ ((fr >> 1) & 3)) * 8);
        }
#pragma unroll
        for (int j = 0; j < 4; j++) {
            const int row = nb + j * 16 + fr;
            bf[j] = *(const short8*)(Bs + row * 32 + (fq ^ ((fr >> 1) & 3)) * 8);
        }
#pragma unroll
        for (int i = 0; i < 4; i++)
#pragma unroll
            for (int j = 0; j < 4; j++)
                acc[i * 4 + j] = __builtin_amdgcn_mfma_f32_16x16x32_bf16(
                    af[i], bf[j], acc[i * 4 + j], 0, 0, 0);
    }

    const int nidx = (bm + mb) >> 6;
#pragma unroll
    for (int j = 0; j < 4; j++) {
        const int n = bn + nb + j * 16 + fr;
        const float bv = bias[n];
        float s = 0.f;
#pragma unroll
        for (int i = 0; i < 4; i++) {
            const f32x4 a = acc[i * 4 + j];
#pragma unroll
            for (int r = 0; r < 4; r++) s += fmaxf(a[r] + bv, 0.f);
        }
        s += __shfl_xor(s, 16);
        s += __shfl_xor(s, 32);
        if (fq == 0) cmean[(size_t)nidx * 1024 + n] = s * (1.0f / 64.0f);
    }
}

// ---------- graph stage r5a: batched precompute (GEMM-style) ----------
// 512 blocks x 4 waves; block stages 64 rows (4 graphs) of obj ONCE into LDS
// (coalesced full-line, XOR-swizzled). Wave 1 -> t1 (x@W1) for all 4 graphs
// (W rows loaded once, reused 4x); wave 2 -> t3; waves 0/3 -> S = x@x^T and
// obj column sums for 2 graphs each. Kills the 3x redundant x reads and 4x
// redundant W reads of the old fused kernel.
__global__ __launch_bounds__(256)
void graph_pre(const ushort_t* __restrict__ obj,
               const ushort_t* __restrict__ W1t, const ushort_t* __restrict__ W3t,
               float* __restrict__ Sg, float* __restrict__ t1g,
               float* __restrict__ t3g, float* __restrict__ omsg)
{
    __shared__ __align__(16) ushort_t Xs[64 * 512];   // 64KB
    const int t = threadIdx.x;
    const int lane = t & 63, w = t >> 6;
    const int bm = blockIdx.x * 64;
    const int g0 = blockIdx.x * 4;
    const int fr = lane & 15, fq = lane >> 4;

    // stage: each wave-instr reads one full 1KB row
#pragma unroll
    for (int i = 0; i < 16; i++) {
        const int flat = i * 256 + t;
        const int row = flat >> 6, c = flat & 63;
        const uint4 v = *(const uint4*)(obj + (size_t)(bm + row) * 512 + c * 8);
        *(uint4*)&Xs[row * 512 + ((c ^ (row & 7)) * 8)] = v;
    }
    __syncthreads();

    if (w == 1 || w == 2) {
        const ushort_t* Wt = (w == 1) ? W1t : W3t;
        float* outp       = (w == 1) ? t1g : t3g;
        f32x4 a0[4], a1[4];
#pragma unroll
        for (int g = 0; g < 4; g++) { a0[g] = (f32x4){0.f,0.f,0.f,0.f}; a1[g] = a0[g]; }
        for (int kk = 0; kk < 16; kk++) {
            const short8 wa = *(const short8*)(Wt + (size_t)fr * 512 + kk * 32 + fq * 8);
            const short8 wb = *(const short8*)(Wt + (size_t)(16 + fr) * 512 + kk * 32 + fq * 8);
#pragma unroll
            for (int g = 0; g < 4; g++) {
                const short8 af = *(const short8*)&Xs[(g * 16 + fr) * 512 + (((kk * 4 + fq) ^ (fr & 7)) * 8)];
                a0[g] = __builtin_amdgcn_mfma_f32_16x16x32_bf16(af, wa, a0[g], 0, 0, 0);
                a1[g] = __builtin_amdgcn_mfma_f32_16x16x32_bf16(af, wb, a1[g], 0, 0, 0);
            }
        }
#pragma unroll
        for (int g = 0; g < 4; g++) {
#pragma unroll
            for (int i = 0; i < 4; i++) {
                const int m = fq * 4 + i;
                outp[(size_t)(g0 + g) * 512 + m * 32 + fr]      = a0[g][i];
                outp[(size_t)(g0 + g) * 512 + m * 32 + 16 + fr] = a1[g][i];
            }
        }
    } else {
        const int gb = (w == 0) ? 0 : 2;
        f32x4 s0 = (f32x4){0.f,0.f,0.f,0.f}, s1 = s0;
        for (int kk = 0; kk < 16; kk++) {
            const short8 af0 = *(const short8*)&Xs[(gb * 16 + fr) * 512 + (((kk * 4 + fq) ^ (fr & 7)) * 8)];
            const short8 af1 = *(const short8*)&Xs[((gb + 1) * 16 + fr) * 512 + (((kk * 4 + fq) ^ (fr & 7)) * 8)];
            s0 = __builtin_amdgcn_mfma_f32_16x16x32_bf16(af0, af0, s0, 0, 0, 0);
            s1 = __builtin_amdgcn_mfma_f32_16x16x32_bf16(af1, af1, s1, 0, 0, 0);
        }
#pragma unroll
        for (int i = 0; i < 4; i++) {
            const int m = fq * 4 + i;
            Sg[(size_t)(g0 + gb) * 256 + m * 16 + fr]     = s0[i];
            Sg[(size_t)(g0 + gb + 1) * 256 + m * 16 + fr] = s1[i];
        }
        // obj column sums for graphs gb, gb+1
#pragma unroll
        for (int gg = 0; gg < 2; gg++) {
            const int g = gb + gg;
            float om[8] = {0,0,0,0,0,0,0,0};
#pragma unroll
            for (int m = 0; m < 16; m++) {
                const uint4 q = *(const uint4*)&Xs[(g * 16 + m) * 512 + ((lane ^ (m & 7)) * 8)];
                om[0] += bflo(q.x); om[1] += bfhi(q.x);
                om[2] += bflo(q.y); om[3] += bfhi(q.y);
                om[4] += bflo(q.z); om[5] += bfhi(q.z);
                om[6] += bflo(q.w); om[7] += bfhi(q.w);
            }
            *(float4*)(omsg + (size_t)(g0 + g) * 512 + lane * 8)     = (float4){om[0], om[1], om[2], om[3]};
            *(float4*)(omsg + (size_t)(g0 + g) * 512 + lane * 8 + 4) = (float4){om[4], om[5], om[6], om[7]};
        }
    }
}

// ---------- graph stage r5b: per-graph finish, one wave, barrier-free ----------
// Reads only tiny precomputed arrays (9KB/graph) + L2-hot W2/W4. All
// reductions intra-wave shfl_xor trees; __syncthreads in a 64-thread block
// compiles to waitcnt only (single wave).
__global__ __launch_bounds__(64)
void graph_fin(const float* __restrict__ Sg, const float* __restrict__ t1g,
               const float* __restrict__ t3g, const float* __restrict__ omsg,
               const float* __restrict__ b1, const float* __restrict__ b3,
               const ushort_t* __restrict__ W2b, const float* __restrict__ b2,
               const ushort_t* __restrict__ W4b, const float* __restrict__ b4,
               ushort_t* __restrict__ cbuf)
{
    __shared__ float t1S[16 * 36], t3S[16 * 36], y2S[16 * 36];
    __shared__ float adjS[16 * 17];
    __shared__ float dvS[16], cAS[16], nrmS[16], dv3S[16], cA3S[16];
    __shared__ float zc1S[32], zc4S[32];

    const int lane = threadIdx.x;
    const int r = lane & 15, q = lane >> 4;
    const int g = blockIdx.x;

    // stage t1,t3 [16][32] -> LDS stride 36
    {
        const int row = lane >> 2, cb = (lane & 3) * 8;
        const float4 a0 = *(const float4*)(t1g + (size_t)g * 512 + lane * 8);
        const float4 a1 = *(const float4*)(t1g + (size_t)g * 512 + lane * 8 + 4);
        const float4 c0v = *(const float4*)(t3g + (size_t)g * 512 + lane * 8);
        const float4 c1v = *(const float4*)(t3g + (size_t)g * 512 + lane * 8 + 4);
        *(float4*)&t1S[row * 36 + cb]     = a0;
        *(float4*)&t1S[row * 36 + cb + 4] = a1;
        *(float4*)&t3S[row * 36 + cb]     = c0v;
        *(float4*)&t3S[row * 36 + cb + 4] = c1v;
    }

    // P1: softmax over row r of S (lane holds cols q*4..q*4+3)
    const float4 sv = *(const float4*)(Sg + (size_t)g * 256 + r * 16 + q * 4);
    float mx = fmaxf(fmaxf(sv.x, sv.y), fmaxf(sv.z, sv.w));
    mx = fmaxf(mx, __shfl_xor(mx, 16));
    mx = fmaxf(mx, __shfl_xor(mx, 32));
    const float e0 = expf(sv.x - mx), e1 = expf(sv.y - mx);
    const float e2 = expf(sv.z - mx), e3 = expf(sv.w - mx);
    float rs = e0 + e1 + e2 + e3;
    rs += __shfl_xor(rs, 16); rs += __shfl_xor(rs, 32);
    const float dv = rsqrtf(rs);
    if (q == 0) dvS[r] = dv;
    __syncthreads();

    // P2: adj + fused column sums cA
    float ad0, ad1, ad2, ad3;
    {
        const float4 dc = *(const float4*)&dvS[q * 4];
        ad0 = e0 * dv * dc.x; ad1 = e1 * dv * dc.y;
        ad2 = e2 * dv * dc.z; ad3 = e3 * dv * dc.w;
    }
    adjS[r * 17 + q * 4 + 0] = ad0; adjS[r * 17 + q * 4 + 1] = ad1;
    adjS[r * 17 + q * 4 + 2] = ad2; adjS[r * 17 + q * 4 + 3] = ad3;
    {
        float c0s = ad0, c1s = ad1, c2s = ad2, c3s = ad3;
#pragma unroll
        for (int m = 1; m <= 8; m <<= 1) {
            c0s += __shfl_xor(c0s, m); c1s += __shfl_xor(c1s, m);
            c2s += __shfl_xor(c2s, m); c3s += __shfl_xor(c3s, m);
        }
        if (r == 0) {
            cAS[q * 4 + 0] = c0s; cAS[q * 4 + 1] = c1s;
            cAS[q * 4 + 2] = c2s; cAS[q * 4 + 3] = c3s;
        }
    }
    __syncthreads();

    // P3: x1 = relu(adj@t1 + b1), y2 = relu(adj@t3 + b3); row r, cols q*8..q*8+7
    const int c0 = q * 8;
    float x1v[8], y2v[8];
    {
        const float4 b1a = *(const float4*)(b1 + c0);
        const float4 b1b = *(const float4*)(b1 + c0 + 4);
        const float4 b3a = *(const float4*)(b3 + c0);
        const float4 b3b = *(const float4*)(b3 + c0 + 4);
        x1v[0]=b1a.x; x1v[1]=b1a.y; x1v[2]=b1a.z; x1v[3]=b1a.w;
        x1v[4]=b1b.x; x1v[5]=b1b.y; x1v[6]=b1b.z; x1v[7]=b1b.w;
        y2v[0]=b3a.x; y2v[1]=b3a.y; y2v[2]=b3a.z; y2v[3]=b3a.w;
        y2v[4]=b3b.x; y2v[5]=b3b.y; y2v[6]=b3b.z; y2v[7]=b3b.w;
    }
#pragma unroll
    for (int j = 0; j < 16; j++) {
        const float a = adjS[r * 17 + j];
        const float4 t1a = *(const float4*)&t1S[j * 36 + c0];
        const float4 t1b = *(const float4*)&t1S[j * 36 + c0 + 4];
        const float4 t3a = *(const float4*)&t3S[j * 36 + c0];
        const float4 t3b = *(const float4*)&t3S[j * 36 + c0 + 4];
        x1v[0] = fmaf(a, t1a.x, x1v[0]); x1v[1] = fmaf(a, t1a.y, x1v[1]);
        x1v[2] = fmaf(a, t1a.z, x1v[2]); x1v[3] = fmaf(a, t1a.w, x1v[3]);
        x1v[4] = fmaf(a, t1b.x, x1v[4]); x1v[5] = fmaf(a, t1b.y, x1v[5]);
        x1v[6] = fmaf(a, t1b.z, x1v[6]); x1v[7] = fmaf(a, t1b.w, x1v[7]);
        y2v[0] = fmaf(a, t3a.x, y2v[0]); y2v[1] = fmaf(a, t3a.y, y2v[1]);
        y2v[2] = fmaf(a, t3a.z, y2v[2]); y2v[3] = fmaf(a, t3a.w, y2v[3]);
        y2v[4] = fmaf(a, t3b.x, y2v[4]); y2v[5] = fmaf(a, t3b.y, y2v[5]);
        y2v[6] = fmaf(a, t3b.z, y2v[6]); y2v[7] = fmaf(a, t3b.w, y2v[7]);
    }
#pragma unroll
    for (int cc = 0; cc < 8; cc++) {
        x1v[cc] = fmaxf(x1v[cc], 0.f);
        y2v[cc] = fmaxf(y2v[cc], 0.f);
        y2S[r * 36 + c0 + cc] = y2v[cc];
    }
    __syncthreads();

    // P4: y22[r][q*4+i] = dot(y2 row r, row q*4+i) + fused row-norm
    float yy[4] = {0.f, 0.f, 0.f, 0.f};
#pragma unroll
    for (int k4 = 0; k4 < 8; k4++) {
        const float4 yi = *(const float4*)&y2S[r * 36 + k4 * 4];
#pragma unroll
        for (int i = 0; i < 4; i++) {
            const float4 yj = *(const float4*)&y2S[(q * 4 + i) * 36 + k4 * 4];
            yy[i] = fmaf(yi.x, yj.x, yy[i]); yy[i] = fmaf(yi.y, yj.y, yy[i]);
            yy[i] = fmaf(yi.z, yj.z, yy[i]); yy[i] = fmaf(yi.w, yj.w, yy[i]);
        }
    }
    {
        float sq = 0.f;
#pragma unroll
        for (int i = 0; i < 4; i++) sq = fmaf(yy[i], yy[i], sq);
        sq += __shfl_xor(sq, 16); sq += __shfl_xor(sq, 32);
        const float nr = sqrtf(sq);
        if (q == 0) nrmS[r] = nr;
    }
    __syncthreads();

    // P5: adj3 + fused row-degree dv3
    float a3[4];
    float dv3;
    {
        const float nr = nrmS[r];
        const float4 ncv = *(const float4*)&nrmS[q * 4];
        a3[0] = 1.0f + yy[0] / (nr * ncv.x);
        a3[1] = 1.0f + yy[1] / (nr * ncv.y);
        a3[2] = 1.0f + yy[2] / (nr * ncv.z);
        a3[3] = 1.0f + yy[3] / (nr * ncv.w);
        float d3 = a3[0] + a3[1] + a3[2] + a3[3];
        d3 += __shfl_xor(d3, 16); d3 += __shfl_xor(d3, 32);
        dv3 = rsqrtf(d3);
        if (q == 0) dv3S[r] = dv3;
    }
    // zc1[c] = sum_m cA[m]*x1[m][c]  (reduce over same-q lanes = rows)
    {
        const float cAm = cAS[r];
        float zp[8];
#pragma unroll
        for (int cc = 0; cc < 8; cc++) zp[cc] = cAm * x1v[cc];
#pragma unroll
        for (int m = 1; m <= 8; m <<= 1)
#pragma unroll
            for (int cc = 0; cc < 8; cc++) zp[cc] += __shfl_xor(zp[cc], m);
        if (r == 0)
#pragma unroll
            for (int cc = 0; cc < 8; cc++) zc1S[c0 + cc] = zp[cc];
    }
    __syncthreads();

    // P6: cA3[c] = sum_r a3[r][c]*dv3[r]*dv3[c]
    {
        const float4 d3c = *(const float4*)&dv3S[q * 4];
        float p0 = a3[0] * dv3 * d3c.x, p1 = a3[1] * dv3 * d3c.y;
        float p2 = a3[2] * dv3 * d3c.z, p3 = a3[3] * dv3 * d3c.w;
#pragma unroll
        for (int m = 1; m <= 8; m <<= 1) {
            p0 += __shfl_xor(p0, m); p1 += __shfl_xor(p1, m);
            p2 += __shfl_xor(p2, m); p3 += __shfl_xor(p3, m);
        }
        if (r == 0) {
            cA3S[q * 4 + 0] = p0; cA3S[q * 4 + 1] = p1;
            cA3S[q * 4 + 2] = p2; cA3S[q * 4 + 3] = p3;
        }
    }
    __syncthreads();

    // P7: zc4[c] = sum_m cA3[m]*y2[m][c]
    {
        const float cA3m = cA3S[r];
        float zp[8];
#pragma unroll
        for (int cc = 0; cc < 8; cc++) zp[cc] = cA3m * y2v[cc];
#pragma unroll
        for (int m = 1; m <= 8; m <<= 1)
#pragma unroll
            for (int cc = 0; cc < 8; cc++) zp[cc] += __shfl_xor(zp[cc], m);
        if (r == 0)
#pragma unroll
            for (int cc = 0; cc < 8; cc++) zc4S[c0 + cc] = zp[cc];
    }
    __syncthreads();

    // P8: GEMV over W2/W4 (cols lane*8..lane*8+7) + combine + store
    {
        float gm[8] = {0,0,0,0,0,0,0,0};
        const ushort_t* w2p = W2b + lane * 8;
        const ushort_t* w4p = W4b + lane * 8;
#pragma unroll 8
        for (int k = 0; k < 32; k++) {
            const float z1 = zc1S[k], z4 = zc4S[k];
            const uint4 u2 = *(const uint4*)(w2p + (size_t)k * 512);
            const uint4 u4 = *(const uint4*)(w4p + (size_t)k * 512);
            gm[0] = fmaf(z1, bflo(u2.x), gm[0]); gm[0] = fmaf(z4, bflo(u4.x), gm[0]);
            gm[1] = fmaf(z1, bfhi(u2.x), gm[1]); gm[1] = fmaf(z4, bfhi(u4.x), gm[1]);
            gm[2] = fmaf(z1, bflo(u2.y), gm[2]); gm[2] = fmaf(z4, bflo(u4.y), gm[2]);
            gm[3] = fmaf(z1, bfhi(u2.y), gm[3]); gm[3] = fmaf(z4, bfhi(u4.y), gm[3]);
            gm[4] = fmaf(z1, bflo(u2.z), gm[4]); gm[4] = fmaf(z4, bflo(u4.z), gm[4]);
            gm[5] = fmaf(z1, bfhi(u2.z), gm[5]); gm[5] = fmaf(z4, bfhi(u4.z), gm[5]);
            gm[6] = fmaf(z1, bflo(u2.w), gm[6]); gm[6] = fmaf(z4, bflo(u4.w), gm[6]);
            gm[7] = fmaf(z1, bfhi(u2.w), gm[7]); gm[7] = fmaf(z4, bfhi(u4.w), gm[7]);
        }
        const float4 oma = *(const float4*)(omsg + (size_t)g * 512 + lane * 8);
        const float4 omb = *(const float4*)(omsg + (size_t)g * 512 + lane * 8 + 4);
        const float om[8] = {oma.x, oma.y, oma.z, oma.w, omb.x, omb.y, omb.z, omb.w};
        const float4 b2a = *(const float4*)(b2 + lane * 8);
        const float4 b2b = *(const float4*)(b2 + lane * 8 + 4);
        const float4 b4a = *(const float4*)(b4 + lane * 8);
        const float4 b4b = *(const float4*)(b4 + lane * 8 + 4);
        const float bs[8] = { b2a.x + b4a.x, b2a.y + b4a.y, b2a.z + b4a.z, b2a.w + b4a.w,
                              b2b.x + b4b.x, b2b.y + b4b.y, b2b.z + b4b.z, b2b.w + b4b.w };
        ushort_t pk[8];
#pragma unroll
        for (int cc = 0; cc < 8; cc++) {
            const float gmean = 0.5f * bs[cc] + gm[cc] * (1.0f / 32.0f);
            const float feat  = 0.5f * (om[cc] * 0.0625f + gmean);
            pk[cc] = f2bf(fmaxf(feat, 0.f));
        }
        *(uint4*)(cbuf + (size_t)g * 512 + lane * 8) = *(uint4*)pk;
    }
}

// ---------- clf GEMV on transposed W ----------
__global__ __launch_bounds__(256)
void clf_col(const float* __restrict__ cmean, const float* __restrict__ Wt,
             const float* __restrict__ clf_b, float* __restrict__ out)
{
    __shared__ float red[8][33];
    const int j = blockIdx.x;
    const int t = threadIdx.x;
    const int n = t & 31, kp = t >> 5;
    const float* cm = cmean + (size_t)n * 1024 + kp * 128;
    const float* wp = Wt + (size_t)j * 1024 + kp * 128;
    float acc = 0.f;
#pragma unroll
    for (int k = 0; k < 128; k += 4) {
        const float4 c = *(const float4*)(cm + k);
        const float4 wv = *(const float4*)(wp + k);
        acc = fmaf(c.x, wv.x, acc);
        acc = fmaf(c.y, wv.y, acc);
        acc = fmaf(c.z, wv.z, acc);
        acc = fmaf(c.w, wv.w, acc);
    }
    red[kp][n] = acc;
    __syncthreads();
    if (t < 32) {
        float s = red[0][t];
#pragma unroll
        for (int p = 1; p < 8; p++) s += red[p][t];
        out[(size_t)t * 500 + j] = s + clf_b[j];
    }
}

// ---------- launcher ----------
extern "C" void kernel_launch(void* const* d_in, const int* in_sizes, int n_in,
                              void* d_out, int out_size, void* d_ws, size_t ws_size,
                              hipStream_t stream)
{
    const float* object_raw = (const float*)d_in[0];
    const float* action_raw = (const float*)d_in[1];
    const float* W_obj = (const float*)d_in[2];
    const float* b_obj = (const float*)d_in[3];
    const float* W_act = (const float*)d_in[4];
    const float* b_act = (const float*)d_in[5];
    const float* gc1_W = (const float*)d_in[6];
    const float* gc1_b = (const float*)d_in[7];
    const float* gc2_W = (const float*)d_in[8];
    const float* gc2_b = (const float*)d_in[9];
    const float* gc3_W = (const float*)d_in[10];
    const float* gc3_b = (const float*)d_in[11];
    const float* gc4_W = (const float*)d_in[12];
    const float* gc4_b = (const float*)d_in[13];
    const float* fc1_W = (const float*)d_in[14];
    const float* fc1_b = (const float*)d_in[15];
    const float* clf_W = (const float*)d_in[16];
    const float* clf_b = (const float*)d_in[17];

    char* ws = (char*)d_ws;
    const size_t MB = 1024 * 1024;
    ushort_t* obj_bf = (ushort_t*)(ws);                       // 32 MB
    ushort_t* cbuf   = (ushort_t*)(ws + 32 * MB);             // 2 MB
    float*    WclfT  = (float*)   (ws + 34 * MB);             // 2 MB
    float*    cmean  = (float*)   (ws + 38 * MB);             // 128 KB
    ushort_t* WobjT  = (ushort_t*)(ws + 39 * MB);             // 512 KB
    ushort_t* WactT  = (ushort_t*)(ws + 39 * MB + 512 * 1024);
    ushort_t* fc1T   = (ushort_t*)(ws + 40 * MB);             // 1 MB
    ushort_t* W1t    = (ushort_t*)(ws + 41 * MB);
    ushort_t* W3t    = (ushort_t*)(ws + 41 * MB + 32 * 1024);
    ushort_t* W2bf   = (ushort_t*)(ws + 41 * MB + 64 * 1024);
    ushort_t* W4bf   = (ushort_t*)(ws + 41 * MB + 96 * 1024);
    float*    t1g    = (float*)   (ws + 44 * MB);             // 4 MB
    float*    t3g    = (float*)   (ws + 48 * MB);             // 4 MB
    float*    Sg     = (float*)   (ws + 52 * MB);             // 2 MB
    float*    omsg   = (float*)   (ws + 54 * MB);             // 4 MB

    // 1. weight prep
    prep_weights<<<dim3(1584), 256, 0, stream>>>(
        W_obj, WobjT, W_act, WactT, fc1_W, fc1T,
        gc1_W, W1t, gc3_W, W3t, gc2_W, W2bf, gc4_W, W4bf,
        clf_W, WclfT);

    // 2. obj GEMM
    gemm_obj_stream<<<dim3(256), 512, 0, stream>>>(object_raw, WobjT, b_obj, obj_bf);

    // 3. act GEMM writes rows g*16+8
    gemm_dma<1, float><<<dim3(4, 16), 256, 0, stream>>>(
        action_raw, WactT, b_act, obj_bf, 512, 512, 512, 16, 8);

    // 4a. batched precompute: S, t1, t3, obj col-sums
    graph_pre<<<dim3(512), 256, 0, stream>>>(
        obj_bf, W1t, W3t, Sg, t1g, t3g, omsg);

    // 4b. per-graph finish (1 wave/graph, barrier-free)
    graph_fin<<<dim3(2048), 64, 0, stream>>>(
        Sg, t1g, t3g, omsg, gc1_b, gc3_b, W2bf, gc2_b, W4bf, gc4_b, cbuf);

    // 5. cmean = mean_T(relu(cbuf @ fc1_W + fc1_b))
    gemm_fc1_mean<<<dim3(8, 16), 256, 0, stream>>>(cbuf, fc1T, fc1_b, cmean);

    // 6. out = cmean @ clf_W + clf_b
    clf_col<<<dim3(500), 256, 0, stream>>>(cmean, WclfT, clf_b, (float*)d_out);
}

// Round 6
// 223.728 us; speedup vs baseline: 1.0560x; 1.0279x over previous
//
#include <hip/hip_runtime.h>
#include <hip/hip_bf16.h>

using ushort_t = unsigned short;
using f32x4  = __attribute__((ext_vector_type(4))) float;
using short8 = __attribute__((ext_vector_type(8))) short;

// ---------- bf16 helpers ----------
__device__ __forceinline__ float bflo(unsigned p) {
    union { unsigned u; float f; } x; x.u = p << 16; return x.f;
}
__device__ __forceinline__ float bfhi(unsigned p) {
    union { unsigned u; float f; } x; x.u = p & 0xffff0000u; return x.f;
}
__device__ __forceinline__ ushort_t f2bf(float f) {
    __hip_bfloat16 h = __float2bfloat16(f);   // RTNE
    return *(ushort_t*)&h;
}
__device__ __forceinline__ unsigned pk2bf(float lo, float hi) {
    __hip_bfloat162 h = __float22bfloat162_rn({lo, hi});  // RTNE, packed
    return *(unsigned*)&h;
}

// ---------- combined weight prep ----------
__device__ __forceinline__ void tr_tile(const float* __restrict__ S, ushort_t* __restrict__ D,
                                        int K, int N, int Npad, int bx, int by,
                                        int tx, int ty, float* tile /*32*33*/)
{
    const int k0 = by * 32, n0 = bx * 32;
#pragma unroll
    for (int r = 0; r < 4; r++) {
        const int k = k0 + ty + r * 8, n = n0 + tx;
        tile[(ty + r * 8) * 33 + tx] = (k < K && n < N) ? S[(size_t)k * N + n] : 0.f;
    }
    __syncthreads();
#pragma unroll
    for (int r = 0; r < 4; r++) {
        const int n = n0 + ty + r * 8, k = k0 + tx;
        if (n < Npad && k < K) D[(size_t)n * K + k] = f2bf(tile[tx * 33 + ty + r * 8]);
    }
}

// fp32 -> fp32 transpose (for clf_W)
__device__ __forceinline__ void trf_tile(const float* __restrict__ S, float* __restrict__ D,
                                         int K, int N, int bx, int by,
                                         int tx, int ty, float* tile /*32*33*/)
{
    const int k0 = by * 32, n0 = bx * 32;
#pragma unroll
    for (int r = 0; r < 4; r++) {
        const int k = k0 + ty + r * 8, n = n0 + tx;
        tile[(ty + r * 8) * 33 + tx] = (k < K && n < N) ? S[(size_t)k * N + n] : 0.f;
    }
    __syncthreads();
#pragma unroll
    for (int r = 0; r < 4; r++) {
        const int n = n0 + ty + r * 8, k = k0 + tx;
        if (n < N && k < K) D[(size_t)n * K + k] = tile[tx * 33 + ty + r * 8];
    }
}

__global__ __launch_bounds__(256)
void prep_weights(const float* __restrict__ Wobj, ushort_t* __restrict__ WobjT,
                  const float* __restrict__ Wact, ushort_t* __restrict__ WactT,
                  const float* __restrict__ fc1W, ushort_t* __restrict__ fc1T,
                  const float* __restrict__ gc1W, ushort_t* __restrict__ W1t,
                  const float* __restrict__ gc3W, ushort_t* __restrict__ W3t,
                  const float* __restrict__ gc2W, ushort_t* __restrict__ W2bf,
                  const float* __restrict__ gc4W, ushort_t* __restrict__ W4bf,
                  const float* __restrict__ clfW, float* __restrict__ WclfT)
{
    __shared__ float tile[32 * 33];
    const int b = blockIdx.x;
    const int t = threadIdx.x;
    const int tx = t & 31, ty = t >> 5;

    if (b < 1056) {
        const float* S; ushort_t* D; int K, N, Npad, nt, l;
        if      (b < 256)  { S = Wobj; D = WobjT; K = 512; N = 512;  Npad = 512;  nt = 16; l = b; }
        else if (b < 512)  { S = Wact; D = WactT; K = 512; N = 512;  Npad = 512;  nt = 16; l = b - 256; }
        else if (b < 1024) { S = fc1W; D = fc1T;  K = 512; N = 1024; Npad = 1024; nt = 32; l = b - 512; }
        else if (b < 1040) { S = gc1W; D = W1t;   K = 512; N = 32;   Npad = 32;   nt = 1;  l = b - 1024; }
        else               { S = gc3W; D = W3t;   K = 512; N = 32;   Npad = 32;   nt = 1;  l = b - 1040; }
        tr_tile(S, D, K, N, Npad, l % nt, l / nt, tx, ty, tile);
    } else if (b < 1072) {
        const float* S = (b < 1064) ? gc2W : gc4W;
        ushort_t* D    = (b < 1064) ? W2bf : W4bf;
        const int i = (b < 1064 ? b - 1056 : b - 1064) * 256 + t;
        const float4 x = ((const float4*)S)[2 * i];
        const float4 y = ((const float4*)S)[2 * i + 1];
        unsigned r[4] = { pk2bf(x.x, x.y), pk2bf(x.z, x.w), pk2bf(y.x, y.y), pk2bf(y.z, y.w) };
        ((uint4*)D)[i] = *(uint4*)r;
    } else {
        const int l = b - 1072;
        trf_tile(clfW, WclfT, 1024, 500, l & 15, l >> 4, tx, ty, tile);
    }
}

// ---------- generic MFMA GEMM (proven; used for act) ----------
typedef __attribute__((address_space(1))) void glb_void;
typedef __attribute__((address_space(3))) void lds_void;
__device__ __forceinline__ void dma16(const void* g, void* l) {
    __builtin_amdgcn_global_load_lds((glb_void*)(unsigned long long)(uintptr_t)g,
                                     (lds_void*)(unsigned)(uintptr_t)l, 16, 0, 0);
}

template<int RELU, typename AT>
__global__ __launch_bounds__(256)
void gemm_dma(const AT* __restrict__ A, const ushort_t* __restrict__ Bt,
              const float* __restrict__ bias, ushort_t* __restrict__ C,
              int N, int K, int Nb, int row_mul, int row_add)
{
    __shared__ __align__(16) char     AsRaw[128 * 32 * sizeof(AT)];
    __shared__ __align__(16) ushort_t Bs[128 * 32];
    const int t = threadIdx.x;
    const int lane = t & 63, w = t >> 6;
    const int bm = blockIdx.y * 128, bn = blockIdx.x * 128;
    const int mb = (w & 1) * 64, nb = (w >> 1) * 64;
    const int fr = lane & 15, fq = lane >> 4;

    f32x4 acc[16];
#pragma unroll
    for (int i = 0; i < 16; i++) acc[i] = (f32x4){0.f, 0.f, 0.f, 0.f};

    const int brow = lane >> 2, bk = lane & 3;
    const int klog = bk ^ ((brow >> 1) & 3);
    const int arow = lane >> 3, ag = lane & 7;

    for (int k0 = 0; k0 < K; k0 += 32) {
        __syncthreads();
        if constexpr (sizeof(AT) == 4) {
#pragma unroll
            for (int i = 0; i < 4; i++) {
                const int grp = w * 4 + i;
                const int row = grp * 8 + arow;
                const int gl = ag ^ (row & 7);
                dma16((const float*)A + (size_t)(bm + row) * K + k0 + gl * 4,
                      AsRaw + grp * 1024);
            }
        } else {
#pragma unroll
            for (int i = 0; i < 2; i++) {
                const int grp = w * 2 + i;
                const int row = grp * 16 + brow;
                dma16((const ushort_t*)A + (size_t)(bm + row) * K + k0 + klog * 8,
                      (ushort_t*)AsRaw + grp * 512);
            }
        }
#pragma unroll
        for (int i = 0; i < 2; i++) {
            const int grp = w * 2 + i;
            const int row = grp * 16 + brow;
            dma16(Bt + (size_t)(bn + row) * K + k0 + klog * 8, Bs + grp * 512);
        }
        __syncthreads();

        short8 af[4], bf[4];
        if constexpr (sizeof(AT) == 4) {
#pragma unroll
            for (int i = 0; i < 4; i++) {
                const int row = mb + i * 16 + fr;
                const float* base = (const float*)AsRaw + row * 32;
                const f32x4 p0 = *(const f32x4*)(base + (((2 * fq)     ^ (fr & 7)) * 4));
                const f32x4 p1 = *(const f32x4*)(base + (((2 * fq + 1) ^ (fr & 7)) * 4));
                unsigned rr[4] = { pk2bf(p0.x, p0.y), pk2bf(p0.z, p0.w),
                                   pk2bf(p1.x, p1.y), pk2bf(p1.z, p1.w) };
                af[i] = *(short8*)rr;
            }
        } else {
#pragma unroll
            for (int i = 0; i < 4; i++) {
                const int row = mb + i * 16 + fr;
                af[i] = *(const short8*)((const ushort_t*)AsRaw + row * 32 + (fq ^ ((fr >> 1) & 3)) * 8);
            }
        }
#pragma unroll
        for (int j = 0; j < 4; j++) {
            const int row = nb + j * 16 + fr;
            bf[j] = *(const short8*)(Bs + row * 32 + (fq ^ ((fr >> 1) & 3)) * 8);
        }
#pragma unroll
        for (int i = 0; i < 4; i++)
#pragma unroll
            for (int j = 0; j < 4; j++)
                acc[i * 4 + j] = __builtin_amdgcn_mfma_f32_16x16x32_bf16(
                    af[i], bf[j], acc[i * 4 + j], 0, 0, 0);
    }

#pragma unroll
    for (int j = 0; j < 4; j++) {
        const int n = bn + nb + j * 16 + fr;
        const float bv = (n < Nb) ? bias[n] : 0.f;
#pragma unroll
        for (int i = 0; i < 4; i++) {
            const f32x4 a = acc[i * 4 + j];
#pragma unroll
            for (int r = 0; r < 4; r++) {
                const int m = bm + mb + i * 16 + fq * 4 + r;
                float v = a[r] + bv;
                if (RELU) v = fmaxf(v, 0.f);
                C[((size_t)m * row_mul + row_add) * (size_t)N + n] = f2bf(v);
            }
        }
    }
}

// ---------- fc1 GEMM with fused T-mean epilogue (r3-proven) ----------
__global__ __launch_bounds__(256)
void gemm_fc1_mean(const ushort_t* __restrict__ A, const ushort_t* __restrict__ Bt,
                   const float* __restrict__ bias, float* __restrict__ cmean)
{
    __shared__ __align__(16) ushort_t AsS[128 * 32];
    __shared__ __align__(16) ushort_t Bs[128 * 32];
    const int t = threadIdx.x;
    const int lane = t & 63, w = t >> 6;
    const int bm = blockIdx.y * 128, bn = blockIdx.x * 128;
    const int mb = (w & 1) * 64, nb = (w >> 1) * 64;
    const int fr = lane & 15, fq = lane >> 4;
    const int K = 512;

    f32x4 acc[16];
#pragma unroll
    for (int i = 0; i < 16; i++) acc[i] = (f32x4){0.f, 0.f, 0.f, 0.f};

    const int brow = lane >> 2, bk = lane & 3;
    const int klog = bk ^ ((brow >> 1) & 3);

    for (int k0 = 0; k0 < K; k0 += 32) {
        __syncthreads();
#pragma unroll
        for (int i = 0; i < 2; i++) {
            const int grp = w * 2 + i;
            const int row = grp * 16 + brow;
            dma16(A + (size_t)(bm + row) * K + k0 + klog * 8, AsS + grp * 512);
        }
#pragma unroll
        for (int i = 0; i < 2; i++) {
            const int grp = w * 2 + i;
            const int row = grp * 16 + brow;
            dma16(Bt + (size_t)(bn + row) * K + k0 + klog * 8, Bs + grp * 512);
        }
        __syncthreads();

        short8 af[4], bf[4];
#pragma unroll
        for (int i = 0; i < 4; i++) {
            const int row = mb + i * 16 + fr;
            af[i] = *(const short8*)(AsS + row * 32 + (fq ^ ((fr >> 1) & 3)) * 8);
        }
#pragma unroll
        for (int j = 0; j < 4; j++) {
            const int row = nb + j * 16 + fr;
            bf[j] = *(const short8*)(Bs + row * 32 + (fq ^ ((fr >> 1) & 3)) * 8);
        }
#pragma unroll
        for (int i = 0; i < 4; i++)
#pragma unroll
            for (int j = 0; j < 4; j++)
                acc[i * 4 + j] = __builtin_amdgcn_mfma_f32_16x16x32_bf16(
                    af[i], bf[j], acc[i * 4 + j], 0, 0, 0);
    }

    const int nidx = (bm + mb) >> 6;
#pragma unroll
    for (int j = 0; j < 4; j++) {
        const int n = bn + nb + j * 16 + fr;
        const float bv = bias[n];
        float s = 0.f;
#pragma unroll
        for (int i = 0; i < 4; i++) {
            const f32x4 a = acc[i * 4 + j];
#pragma unroll
            for (int r = 0; r < 4; r++) s += fmaxf(a[r] + bv, 0.f);
        }
        s += __shfl_xor(s, 16);
        s += __shfl_xor(s, 32);
        if (fq == 0) cmean[(size_t)nidx * 1024 + n] = s * (1.0f / 64.0f);
    }
}

// ---------- MEGA: obj GEMM + graph pre + graph fin, fused ----------
// A 128-row obj tile = exactly 8 graphs; everything downstream of the obj GEMM
// is block-local. Eliminates obj_bf (32MB W+R) and Sg/t1g/t3g/omsg (14MB W+R)
// plus two launches. Phases: stage A -> MFMA -> C-store in LDS (bf16, (m&7)
// group swizzle) -> inject act rows -> per-wave pre (S/t1/t3/oms into regs) ->
// fp32 handoff overlaid on dead A-tile -> per-wave fin (graph w) -> cbuf.
__global__ __launch_bounds__(512)
void mega_obj_graph(const float* __restrict__ A, const ushort_t* __restrict__ Bt,
                    const float* __restrict__ bias, const ushort_t* __restrict__ act_bf,
                    const ushort_t* __restrict__ W1t, const ushort_t* __restrict__ W3t,
                    const float* __restrict__ b1, const float* __restrict__ b3,
                    const ushort_t* __restrict__ W2b, const float* __restrict__ b2,
                    const ushort_t* __restrict__ W4b, const float* __restrict__ b4,
                    ushort_t* __restrict__ cbuf)
{
    __shared__ __align__(16) ushort_t As[128 * 512];   // 128KB: A-stage -> C-stage -> fp32 handoff
    __shared__ __align__(16) float fsS[8][992];        // 31KB per-wave fin scratch

    const int t = threadIdx.x;
    const int lane = t & 63, w = t >> 6;               // w in 0..7
    const int bm = blockIdx.x * 128;
    const int fr = lane & 15, fq = lane >> 4;

    // ---- A: stage A fp32 -> bf16 LDS, (row&7) group swizzle ----
    const float4* A4 = (const float4*)(A + (size_t)bm * 512);
#pragma unroll
    for (int i = 0; i < 16; i++) {
        const int fl = i * 1024 + t * 2;
        const int row = fl >> 7;
        const float4 p0 = A4[fl];
        const float4 p1 = A4[fl + 1];
        unsigned rr[4] = { pk2bf(p0.x, p0.y), pk2bf(p0.z, p0.w),
                           pk2bf(p1.x, p1.y), pk2bf(p1.z, p1.w) };
        *(uint4*)&As[row * 512 + ((lane ^ (row & 7)) * 8)] = *(uint4*)rr;
    }

    const int nw = w * 64;
    const ushort_t* Bbase = Bt + (size_t)(nw + fr) * 512 + fq * 8;
    uint4 bA[4], bB[4];
#pragma unroll
    for (int j = 0; j < 4; j++) bA[j] = *(const uint4*)(Bbase + (size_t)j * 16 * 512);

    __syncthreads();

    // ---- B: MFMA main loop (r2-proven, B ping-pong) ----
    f32x4 acc[4][8];
#pragma unroll
    for (int j = 0; j < 4; j++)
#pragma unroll
        for (int i = 0; i < 8; i++) acc[j][i] = (f32x4){0.f, 0.f, 0.f, 0.f};

    for (int kk = 0; kk < 16; kk += 2) {
        short8 af[8];
#pragma unroll
        for (int i = 0; i < 8; i++)
            af[i] = *(const short8*)&As[(i * 16 + fr) * 512 + (((kk * 4 + fq) ^ (fr & 7)) * 8)];
#pragma unroll
        for (int j = 0; j < 4; j++) {
            bB[j] = *(const uint4*)(Bbase + (size_t)j * 16 * 512 + (kk + 1) * 32);
            const short8 bf = *(const short8*)&bA[j];
#pragma unroll
            for (int i = 0; i < 8; i++)
                acc[j][i] = __builtin_amdgcn_mfma_f32_16x16x32_bf16(af[i], bf, acc[j][i], 0, 0, 0);
        }
#pragma unroll
        for (int i = 0; i < 8; i++)
            af[i] = *(const short8*)&As[(i * 16 + fr) * 512 + ((((kk + 1) * 4 + fq) ^ (fr & 7)) * 8)];
#pragma unroll
        for (int j = 0; j < 4; j++) {
            if (kk + 2 < 16)
                bA[j] = *(const uint4*)(Bbase + (size_t)j * 16 * 512 + (kk + 2) * 32);
            const short8 bf = *(const short8*)&bB[j];
#pragma unroll
            for (int i = 0; i < 8; i++)
                acc[j][i] = __builtin_amdgcn_mfma_f32_16x16x32_bf16(af[i], bf, acc[j][i], 0, 0, 0);
        }
    }

    // ---- C: bias+relu, bf16 C-store into LDS with (m&7) group swizzle ----
    __syncthreads();
#pragma unroll
    for (int j = 0; j < 4; j++) {
        const int col0 = j * 16 + fr;
        const float bv = bias[nw + col0];
#pragma unroll
        for (int i = 0; i < 8; i++) {
#pragma unroll
            for (int rr2 = 0; rr2 < 4; rr2++) {
                const int m = i * 16 + fq * 4 + rr2;
                const int sw = ((((col0 >> 3) ^ (m & 7)) << 3) | (col0 & 7));
                As[m * 512 + nw + sw] = f2bf(fmaxf(acc[j][i][rr2] + bv, 0.f));
            }
        }
    }
    __syncthreads();

    // ---- D: inject act rows (m = ra*16+8; m&7==0 -> linear) ----
    {
        const int ra = t >> 6, gg = t & 63;
        const uint4 v = *(const uint4*)(act_bf + (size_t)(blockIdx.x * 8 + ra) * 512 + gg * 8);
        *(uint4*)&As[(ra * 16 + 8) * 512 + gg * 8] = v;
    }
    __syncthreads();

    // ---- E: per-wave pre computations into registers ----
    // w1: t1 g0-3 | w5: t1 g4-7 | w2: t3 g0-3 | w6: t3 g4-7
    // w0: S+oms g0-1 | w3: g2-3 | w4: g4-5 | w7: g6-7
    f32x4 e0[4], e1[4];
    float om0[8], om1[8];
    const bool isT = (w == 1) || (w == 2) || (w == 5) || (w == 6);
    const int gofs = (w >= 4) ? 4 : 0;
    const int sidx = (w == 0) ? 0 : (w == 3) ? 1 : (w == 4) ? 2 : 3;   // S-wave id
    const int gb = sidx * 2;

    if (isT) {
        const ushort_t* Wt = ((w & 3) == 1) ? W1t : W3t;
#pragma unroll
        for (int g = 0; g < 4; g++) { e0[g] = (f32x4){0.f,0.f,0.f,0.f}; e1[g] = e0[g]; }
        for (int kk = 0; kk < 16; kk++) {
            const short8 wa = *(const short8*)(Wt + (size_t)fr * 512 + kk * 32 + fq * 8);
            const short8 wb = *(const short8*)(Wt + (size_t)(16 + fr) * 512 + kk * 32 + fq * 8);
#pragma unroll
            for (int g = 0; g < 4; g++) {
                const short8 xf = *(const short8*)&As[((gofs + g) * 16 + fr) * 512 + (((kk * 4 + fq) ^ (fr & 7)) * 8)];
                e0[g] = __builtin_amdgcn_mfma_f32_16x16x32_bf16(xf, wa, e0[g], 0, 0, 0);
                e1[g] = __builtin_amdgcn_mfma_f32_16x16x32_bf16(xf, wb, e1[g], 0, 0, 0);
            }
        }
    } else {
        e0[0] = (f32x4){0.f,0.f,0.f,0.f}; e1[0] = e0[0];
        for (int kk = 0; kk < 16; kk++) {
            const short8 xf0 = *(const short8*)&As[(gb * 16 + fr) * 512 + (((kk * 4 + fq) ^ (fr & 7)) * 8)];
            const short8 xf1 = *(const short8*)&As[((gb + 1) * 16 + fr) * 512 + (((kk * 4 + fq) ^ (fr & 7)) * 8)];
            e0[0] = __builtin_amdgcn_mfma_f32_16x16x32_bf16(xf0, xf0, e0[0], 0, 0, 0);
            e1[0] = __builtin_amdgcn_mfma_f32_16x16x32_bf16(xf1, xf1, e1[0], 0, 0, 0);
        }
#pragma unroll
        for (int c = 0; c < 8; c++) { om0[c] = 0.f; om1[c] = 0.f; }
#pragma unroll
        for (int m = 0; m < 16; m++) {
            const uint4 q0 = *(const uint4*)&As[(gb * 16 + m) * 512 + ((lane ^ (m & 7)) * 8)];
            const uint4 q1 = *(const uint4*)&As[((gb + 1) * 16 + m) * 512 + ((lane ^ (m & 7)) * 8)];
            om0[0] += bflo(q0.x); om0[1] += bfhi(q0.x);
            om0[2] += bflo(q0.y); om0[3] += bfhi(q0.y);
            om0[4] += bflo(q0.z); om0[5] += bfhi(q0.z);
            om0[6] += bflo(q0.w); om0[7] += bfhi(q0.w);
            om1[0] += bflo(q1.x); om1[1] += bfhi(q1.x);
            om1[2] += bflo(q1.y); om1[3] += bfhi(q1.y);
            om1[4] += bflo(q1.z); om1[5] += bfhi(q1.z);
            om1[6] += bflo(q1.w); om1[7] += bfhi(q1.w);
        }
    }
    __syncthreads();   // all reads of C-tile done; As free for fp32 handoff

    // ---- handoff: per graph g (0..7): base g*1792: S[256] t1[512] t3[512] oms[512]
    float* Hs = (float*)As;
    if (isT) {
        const int toff = ((w & 3) == 1) ? 256 : 768;
#pragma unroll
        for (int g = 0; g < 4; g++) {
            float* dst = Hs + (gofs + g) * 1792 + toff;
#pragma unroll
            for (int i = 0; i < 4; i++) {
                const int m = fq * 4 + i;
                dst[m * 32 + fr]      = e0[g][i];
                dst[m * 32 + 16 + fr] = e1[g][i];
            }
        }
    } else {
        float* d0 = Hs + gb * 1792;
        float* d1 = Hs + (gb + 1) * 1792;
#pragma unroll
        for (int i = 0; i < 4; i++) {
            const int m = fq * 4 + i;
            d0[m * 16 + fr] = e0[0][i];
            d1[m * 16 + fr] = e1[0][i];
        }
        *(float4*)(d0 + 1280 + lane * 8)     = (float4){om0[0], om0[1], om0[2], om0[3]};
        *(float4*)(d0 + 1280 + lane * 8 + 4) = (float4){om0[4], om0[5], om0[6], om0[7]};
        *(float4*)(d1 + 1280 + lane * 8)     = (float4){om1[0], om1[1], om1[2], om1[3]};
        *(float4*)(d1 + 1280 + lane * 8 + 4) = (float4){om1[4], om1[5], om1[6], om1[7]};
    }
    __syncthreads();

    // ---- F: fin chain, one wave per graph (graph = w), r5-proven math ----
    {
        const int r = fr, q = fq;
        const float* Hg = Hs + w * 1792;                 // S at 0, t1 at 256, t3 at 768, oms at 1280
        float* fw   = fsS[w];
        float* adjS = fw;            // 16*17 = 272
        float* y2S  = fw + 272;      // 16*36 = 576
        float* dvS  = fw + 848;
        float* cAS  = fw + 864;
        float* nrmS = fw + 880;
        float* dv3S = fw + 896;
        float* cA3S = fw + 912;
        float* zc1S = fw + 928;      // 32
        float* zc4S = fw + 960;      // 32

        // P1: softmax over row r of S
        const float4 sv = *(const float4*)(Hg + r * 16 + q * 4);
        float mx = fmaxf(fmaxf(sv.x, sv.y), fmaxf(sv.z, sv.w));
        mx = fmaxf(mx, __shfl_xor(mx, 16));
        mx = fmaxf(mx, __shfl_xor(mx, 32));
        const float e0s = expf(sv.x - mx), e1s = expf(sv.y - mx);
        const float e2s = expf(sv.z - mx), e3s = expf(sv.w - mx);
        float rs = e0s + e1s + e2s + e3s;
        rs += __shfl_xor(rs, 16); rs += __shfl_xor(rs, 32);
        const float dv = rsqrtf(rs);
        if (q == 0) dvS[r] = dv;
        __syncthreads();

        // P2: adj + fused column sums cA
        float ad0, ad1, ad2, ad3;
        {
            const float4 dc = *(const float4*)&dvS[q * 4];
            ad0 = e0s * dv * dc.x; ad1 = e1s * dv * dc.y;
            ad2 = e2s * dv * dc.z; ad3 = e3s * dv * dc.w;
        }
        adjS[r * 17 + q * 4 + 0] = ad0; adjS[r * 17 + q * 4 + 1] = ad1;
        adjS[r * 17 + q * 4 + 2] = ad2; adjS[r * 17 + q * 4 + 3] = ad3;
        {
            float c0s = ad0, c1s = ad1, c2s = ad2, c3s = ad3;
#pragma unroll
            for (int m = 1; m <= 8; m <<= 1) {
                c0s += __shfl_xor(c0s, m); c1s += __shfl_xor(c1s, m);
                c2s += __shfl_xor(c2s, m); c3s += __shfl_xor(c3s, m);
            }
            if (r == 0) {
                cAS[q * 4 + 0] = c0s; cAS[q * 4 + 1] = c1s;
                cAS[q * 4 + 2] = c2s; cAS[q * 4 + 3] = c3s;
            }
        }
        __syncthreads();

        // P3: x1 = relu(adj@t1 + b1), y2 = relu(adj@t3 + b3); row r, cols q*8..+7
        const int c0 = q * 8;
        float x1v[8], y2v[8];
        {
            const float4 b1a = *(const float4*)(b1 + c0);
            const float4 b1b = *(const float4*)(b1 + c0 + 4);
            const float4 b3a = *(const float4*)(b3 + c0);
            const float4 b3b = *(const float4*)(b3 + c0 + 4);
            x1v[0]=b1a.x; x1v[1]=b1a.y; x1v[2]=b1a.z; x1v[3]=b1a.w;
            x1v[4]=b1b.x; x1v[5]=b1b.y; x1v[6]=b1b.z; x1v[7]=b1b.w;
            y2v[0]=b3a.x; y2v[1]=b3a.y; y2v[2]=b3a.z; y2v[3]=b3a.w;
            y2v[4]=b3b.x; y2v[5]=b3b.y; y2v[6]=b3b.z; y2v[7]=b3b.w;
        }
#pragma unroll
        for (int j = 0; j < 16; j++) {
            const float a = adjS[r * 17 + j];
            const float4 t1a = *(const float4*)(Hg + 256 + j * 32 + c0);
            const float4 t1b = *(const float4*)(Hg + 256 + j * 32 + c0 + 4);
            const float4 t3a = *(const float4*)(Hg + 768 + j * 32 + c0);
            const float4 t3b = *(const float4*)(Hg + 768 + j * 32 + c0 + 4);
            x1v[0] = fmaf(a, t1a.x, x1v[0]); x1v[1] = fmaf(a, t1a.y, x1v[1]);
            x1v[2] = fmaf(a, t1a.z, x1v[2]); x1v[3] = fmaf(a, t1a.w, x1v[3]);
            x1v[4] = fmaf(a, t1b.x, x1v[4]); x1v[5] = fmaf(a, t1b.y, x1v[5]);
            x1v[6] = fmaf(a, t1b.z, x1v[6]); x1v[7] = fmaf(a, t1b.w, x1v[7]);
            y2v[0] = fmaf(a, t3a.x, y2v[0]); y2v[1] = fmaf(a, t3a.y, y2v[1]);
            y2v[2] = fmaf(a, t3a.z, y2v[2]); y2v[3] = fmaf(a, t3a.w, y2v[3]);
            y2v[4] = fmaf(a, t3b.x, y2v[4]); y2v[5] = fmaf(a, t3b.y, y2v[5]);
            y2v[6] = fmaf(a, t3b.z, y2v[6]); y2v[7] = fmaf(a, t3b.w, y2v[7]);
        }
#pragma unroll
        for (int cc = 0; cc < 8; cc++) {
            x1v[cc] = fmaxf(x1v[cc], 0.f);
            y2v[cc] = fmaxf(y2v[cc], 0.f);
            y2S[r * 36 + c0 + cc] = y2v[cc];
        }
        __syncthreads();

        // P4: y22 row-dot + fused row-norm
        float yy[4] = {0.f, 0.f, 0.f, 0.f};
#pragma unroll
        for (int k4 = 0; k4 < 8; k4++) {
            const float4 yi = *(const float4*)&y2S[r * 36 + k4 * 4];
#pragma unroll
            for (int i = 0; i < 4; i++) {
                const float4 yj = *(const float4*)&y2S[(q * 4 + i) * 36 + k4 * 4];
                yy[i] = fmaf(yi.x, yj.x, yy[i]); yy[i] = fmaf(yi.y, yj.y, yy[i]);
                yy[i] = fmaf(yi.z, yj.z, yy[i]); yy[i] = fmaf(yi.w, yj.w, yy[i]);
            }
        }
        {
            float sq = 0.f;
#pragma unroll
            for (int i = 0; i < 4; i++) sq = fmaf(yy[i], yy[i], sq);
            sq += __shfl_xor(sq, 16); sq += __shfl_xor(sq, 32);
            const float nr = sqrtf(sq);
            if (q == 0) nrmS[r] = nr;
        }
        __syncthreads();

        // P5: adj3 + fused degree dv3; zc1 via row-reduce of cA*x1
        float a3[4];
        float dv3;
        {
            const float nr = nrmS[r];
            const float4 ncv = *(const float4*)&nrmS[q * 4];
            a3[0] = 1.0f + yy[0] / (nr * ncv.x);
            a3[1] = 1.0f + yy[1] / (nr * ncv.y);
            a3[2] = 1.0f + yy[2] / (nr * ncv.z);
            a3[3] = 1.0f + yy[3] / (nr * ncv.w);
            float d3 = a3[0] + a3[1] + a3[2] + a3[3];
            d3 += __shfl_xor(d3, 16); d3 += __shfl_xor(d3, 32);
            dv3 = rsqrtf(d3);
            if (q == 0) dv3S[r] = dv3;
        }
        {
            const float cAm = cAS[r];
            float zp[8];
#pragma unroll
            for (int cc = 0; cc < 8; cc++) zp[cc] = cAm * x1v[cc];
#pragma unroll
            for (int m = 1; m <= 8; m <<= 1)
#pragma unroll
                for (int cc = 0; cc < 8; cc++) zp[cc] += __shfl_xor(zp[cc], m);
            if (r == 0)
#pragma unroll
                for (int cc = 0; cc < 8; cc++) zc1S[c0 + cc] = zp[cc];
        }
        __syncthreads();

        // P6: cA3
        {
            const float4 d3c = *(const float4*)&dv3S[q * 4];
            float p0 = a3[0] * dv3 * d3c.x, p1 = a3[1] * dv3 * d3c.y;
            float p2 = a3[2] * dv3 * d3c.z, p3 = a3[3] * dv3 * d3c.w;
#pragma unroll
            for (int m = 1; m <= 8; m <<= 1) {
                p0 += __shfl_xor(p0, m); p1 += __shfl_xor(p1, m);
                p2 += __shfl_xor(p2, m); p3 += __shfl_xor(p3, m);
            }
            if (r == 0) {
                cA3S[q * 4 + 0] = p0; cA3S[q * 4 + 1] = p1;
                cA3S[q * 4 + 2] = p2; cA3S[q * 4 + 3] = p3;
            }
        }
        __syncthreads();

        // P7: zc4
        {
            const float cA3m = cA3S[r];
            float zp[8];
#pragma unroll
            for (int cc = 0; cc < 8; cc++) zp[cc] = cA3m * y2v[cc];
#pragma unroll
            for (int m = 1; m <= 8; m <<= 1)
#pragma unroll
                for (int cc = 0; cc < 8; cc++) zp[cc] += __shfl_xor(zp[cc], m);
            if (r == 0)
#pragma unroll
                for (int cc = 0; cc < 8; cc++) zc4S[c0 + cc] = zp[cc];
        }
        __syncthreads();

        // P8: GEMV over W2/W4 + combine + store
        {
            float gm[8] = {0,0,0,0,0,0,0,0};
            const ushort_t* w2p = W2b + lane * 8;
            const ushort_t* w4p = W4b + lane * 8;
#pragma unroll 8
            for (int k = 0; k < 32; k++) {
                const float z1 = zc1S[k], z4 = zc4S[k];
                const uint4 u2 = *(const uint4*)(w2p + (size_t)k * 512);
                const uint4 u4 = *(const uint4*)(w4p + (size_t)k * 512);
                gm[0] = fmaf(z1, bflo(u2.x), gm[0]); gm[0] = fmaf(z4, bflo(u4.x), gm[0]);
                gm[1] = fmaf(z1, bfhi(u2.x), gm[1]); gm[1] = fmaf(z4, bfhi(u4.x), gm[1]);
                gm[2] = fmaf(z1, bflo(u2.y), gm[2]); gm[2] = fmaf(z4, bflo(u4.y), gm[2]);
                gm[3] = fmaf(z1, bfhi(u2.y), gm[3]); gm[3] = fmaf(z4, bfhi(u4.y), gm[3]);
                gm[4] = fmaf(z1, bflo(u2.z), gm[4]); gm[4] = fmaf(z4, bflo(u4.z), gm[4]);
                gm[5] = fmaf(z1, bfhi(u2.z), gm[5]); gm[5] = fmaf(z4, bfhi(u4.z), gm[5]);
                gm[6] = fmaf(z1, bflo(u2.w), gm[6]); gm[6] = fmaf(z4, bflo(u4.w), gm[6]);
                gm[7] = fmaf(z1, bfhi(u2.w), gm[7]); gm[7] = fmaf(z4, bfhi(u4.w), gm[7]);
            }
            const float4 oma = *(const float4*)(Hg + 1280 + lane * 8);
            const float4 omb = *(const float4*)(Hg + 1280 + lane * 8 + 4);
            const float om[8] = {oma.x, oma.y, oma.z, oma.w, omb.x, omb.y, omb.z, omb.w};
            const float4 b2a = *(const float4*)(b2 + lane * 8);
            const float4 b2b = *(const float4*)(b2 + lane * 8 + 4);
            const float4 b4a = *(const float4*)(b4 + lane * 8);
            const float4 b4b = *(const float4*)(b4 + lane * 8 + 4);
            const float bs[8] = { b2a.x + b4a.x, b2a.y + b4a.y, b2a.z + b4a.z, b2a.w + b4a.w,
                                  b2b.x + b4b.x, b2b.y + b4b.y, b2b.z + b4b.z, b2b.w + b4b.w };
            ushort_t pk[8];
#pragma unroll
            for (int cc = 0; cc < 8; cc++) {
                const float gmean = 0.5f * bs[cc] + gm[cc] * (1.0f / 32.0f);
                const float feat  = 0.5f * (om[cc] * 0.0625f + gmean);
                pk[cc] = f2bf(fmaxf(feat, 0.f));
            }
            *(uint4*)(cbuf + (size_t)(blockIdx.x * 8 + w) * 512 + lane * 8) = *(uint4*)pk;
        }
    }
}

// ---------- clf GEMV on transposed W ----------
__global__ __launch_bounds__(256)
void clf_col(const float* __restrict__ cmean, const float* __restrict__ Wt,
             const float* __restrict__ clf_b, float* __restrict__ out)
{
    __shared__ float red[8][33];
    const int j = blockIdx.x;
    const int t = threadIdx.x;
    const int n = t & 31, kp = t >> 5;
    const float* cm = cmean + (size_t)n * 1024 + kp * 128;
    const float* wp = Wt + (size_t)j * 1024 + kp * 128;
    float acc = 0.f;
#pragma unroll
    for (int k = 0; k < 128; k += 4) {
        const float4 c = *(const float4*)(cm + k);
        const float4 wv = *(const float4*)(wp + k);
        acc = fmaf(c.x, wv.x, acc);
        acc = fmaf(c.y, wv.y, acc);
        acc = fmaf(c.z, wv.z, acc);
        acc = fmaf(c.w, wv.w, acc);
    }
    red[kp][n] = acc;
    __syncthreads();
    if (t < 32) {
        float s = red[0][t];
#pragma unroll
        for (int p = 1; p < 8; p++) s += red[p][t];
        out[(size_t)t * 500 + j] = s + clf_b[j];
    }
}

// ---------- launcher ----------
extern "C" void kernel_launch(void* const* d_in, const int* in_sizes, int n_in,
                              void* d_out, int out_size, void* d_ws, size_t ws_size,
                              hipStream_t stream)
{
    const float* object_raw = (const float*)d_in[0];
    const float* action_raw = (const float*)d_in[1];
    const float* W_obj = (const float*)d_in[2];
    const float* b_obj = (const float*)d_in[3];
    const float* W_act = (const float*)d_in[4];
    const float* b_act = (const float*)d_in[5];
    const float* gc1_W = (const float*)d_in[6];
    const float* gc1_b = (const float*)d_in[7];
    const float* gc2_W = (const float*)d_in[8];
    const float* gc2_b = (const float*)d_in[9];
    const float* gc3_W = (const float*)d_in[10];
    const float* gc3_b = (const float*)d_in[11];
    const float* gc4_W = (const float*)d_in[12];
    const float* gc4_b = (const float*)d_in[13];
    const float* fc1_W = (const float*)d_in[14];
    const float* fc1_b = (const float*)d_in[15];
    const float* clf_W = (const float*)d_in[16];
    const float* clf_b = (const float*)d_in[17];

    char* ws = (char*)d_ws;
    const size_t MB = 1024 * 1024;
    ushort_t* act_bf = (ushort_t*)(ws);                        // 2 MB
    ushort_t* cbuf   = (ushort_t*)(ws + 2 * MB);               // 2 MB
    float*    WclfT  = (float*)   (ws + 4 * MB);               // 2 MB
    float*    cmean  = (float*)   (ws + 6 * MB);               // 128 KB
    ushort_t* WobjT  = (ushort_t*)(ws + 7 * MB);               // 512 KB
    ushort_t* WactT  = (ushort_t*)(ws + 7 * MB + 512 * 1024);  // 512 KB
    ushort_t* fc1T   = (ushort_t*)(ws + 8 * MB);               // 1 MB
    ushort_t* W1t    = (ushort_t*)(ws + 9 * MB);
    ushort_t* W3t    = (ushort_t*)(ws + 9 * MB + 32 * 1024);
    ushort_t* W2bf   = (ushort_t*)(ws + 9 * MB + 64 * 1024);
    ushort_t* W4bf   = (ushort_t*)(ws + 9 * MB + 96 * 1024);

    // 1. weight prep
    prep_weights<<<dim3(1584), 256, 0, stream>>>(
        W_obj, WobjT, W_act, WactT, fc1_W, fc1T,
        gc1_W, W1t, gc3_W, W3t, gc2_W, W2bf, gc4_W, W4bf,
        clf_W, WclfT);

    // 2. act GEMM -> act_bf [2048][512]
    gemm_dma<1, float><<<dim3(4, 16), 256, 0, stream>>>(
        action_raw, WactT, b_act, act_bf, 512, 512, 512, 1, 0);

    // 3. MEGA: obj GEMM + graph pre + graph fin -> cbuf
    mega_obj_graph<<<dim3(256), 512, 0, stream>>>(
        object_raw, WobjT, b_obj, act_bf, W1t, W3t,
        gc1_b, gc3_b, W2bf, gc2_b, W4bf, gc4_b, cbuf);

    // 4. cmean = mean_T(relu(cbuf @ fc1_W + fc1_b))
    gemm_fc1_mean<<<dim3(8, 16), 256, 0, stream>>>(cbuf, fc1T, fc1_b, cmean);

    // 5. out = cmean @ clf_W + clf_b
    clf_col<<<dim3(500), 256, 0, stream>>>(cmean, WclfT, clf_b, (float*)d_out);
}

// Round 7
// 219.736 us; speedup vs baseline: 1.0752x; 1.0182x over previous
//
#include <hip/hip_runtime.h>
#include <hip/hip_bf16.h>

using ushort_t = unsigned short;
using f32x4  = __attribute__((ext_vector_type(4))) float;
using short8 = __attribute__((ext_vector_type(8))) short;

// ---------- bf16 helpers ----------
__device__ __forceinline__ float bflo(unsigned p) {
    union { unsigned u; float f; } x; x.u = p << 16; return x.f;
}
__device__ __forceinline__ float bfhi(unsigned p) {
    union { unsigned u; float f; } x; x.u = p & 0xffff0000u; return x.f;
}
__device__ __forceinline__ ushort_t f2bf(float f) {
    __hip_bfloat16 h = __float2bfloat16(f);   // RTNE
    return *(ushort_t*)&h;
}
__device__ __forceinline__ unsigned pk2bf(float lo, float hi) {
    __hip_bfloat162 h = __float22bfloat162_rn({lo, hi});  // RTNE, packed
    return *(unsigned*)&h;
}

// ---------- combined weight prep ----------
__device__ __forceinline__ void tr_tile(const float* __restrict__ S, ushort_t* __restrict__ D,
                                        int K, int N, int Npad, int bx, int by,
                                        int tx, int ty, float* tile /*32*33*/)
{
    const int k0 = by * 32, n0 = bx * 32;
#pragma unroll
    for (int r = 0; r < 4; r++) {
        const int k = k0 + ty + r * 8, n = n0 + tx;
        tile[(ty + r * 8) * 33 + tx] = (k < K && n < N) ? S[(size_t)k * N + n] : 0.f;
    }
    __syncthreads();
#pragma unroll
    for (int r = 0; r < 4; r++) {
        const int n = n0 + ty + r * 8, k = k0 + tx;
        if (n < Npad && k < K) D[(size_t)n * K + k] = f2bf(tile[tx * 33 + ty + r * 8]);
    }
}

// fp32 -> fp32 transpose (for clf_W)
__device__ __forceinline__ void trf_tile(const float* __restrict__ S, float* __restrict__ D,
                                         int K, int N, int bx, int by,
                                         int tx, int ty, float* tile /*32*33*/)
{
    const int k0 = by * 32, n0 = bx * 32;
#pragma unroll
    for (int r = 0; r < 4; r++) {
        const int k = k0 + ty + r * 8, n = n0 + tx;
        tile[(ty + r * 8) * 33 + tx] = (k < K && n < N) ? S[(size_t)k * N + n] : 0.f;
    }
    __syncthreads();
#pragma unroll
    for (int r = 0; r < 4; r++) {
        const int n = n0 + ty + r * 8, k = k0 + tx;
        if (n < N && k < K) D[(size_t)n * K + k] = tile[tx * 33 + ty + r * 8];
    }
}

__global__ __launch_bounds__(256)
void prep_weights(const float* __restrict__ Wobj, ushort_t* __restrict__ WobjT,
                  const float* __restrict__ Wact, ushort_t* __restrict__ WactT,
                  const float* __restrict__ fc1W, ushort_t* __restrict__ fc1T,
                  const float* __restrict__ gc1W, ushort_t* __restrict__ W1t,
                  const float* __restrict__ gc3W, ushort_t* __restrict__ W3t,
                  const float* __restrict__ gc2W, ushort_t* __restrict__ W2bf,
                  const float* __restrict__ gc4W, ushort_t* __restrict__ W4bf,
                  const float* __restrict__ clfW, float* __restrict__ WclfT)
{
    __shared__ float tile[32 * 33];
    const int b = blockIdx.x;
    const int t = threadIdx.x;
    const int tx = t & 31, ty = t >> 5;

    if (b < 1056) {
        const float* S; ushort_t* D; int K, N, Npad, nt, l;
        if      (b < 256)  { S = Wobj; D = WobjT; K = 512; N = 512;  Npad = 512;  nt = 16; l = b; }
        else if (b < 512)  { S = Wact; D = WactT; K = 512; N = 512;  Npad = 512;  nt = 16; l = b - 256; }
        else if (b < 1024) { S = fc1W; D = fc1T;  K = 512; N = 1024; Npad = 1024; nt = 32; l = b - 512; }
        else if (b < 1040) { S = gc1W; D = W1t;   K = 512; N = 32;   Npad = 32;   nt = 1;  l = b - 1024; }
        else               { S = gc3W; D = W3t;   K = 512; N = 32;   Npad = 32;   nt = 1;  l = b - 1040; }
        tr_tile(S, D, K, N, Npad, l % nt, l / nt, tx, ty, tile);
    } else if (b < 1072) {
        const float* S = (b < 1064) ? gc2W : gc4W;
        ushort_t* D    = (b < 1064) ? W2bf : W4bf;
        const int i = (b < 1064 ? b - 1056 : b - 1064) * 256 + t;
        const float4 x = ((const float4*)S)[2 * i];
        const float4 y = ((const float4*)S)[2 * i + 1];
        unsigned r[4] = { pk2bf(x.x, x.y), pk2bf(x.z, x.w), pk2bf(y.x, y.y), pk2bf(y.z, y.w) };
        ((uint4*)D)[i] = *(uint4*)r;
    } else {
        const int l = b - 1072;
        trf_tile(clfW, WclfT, 1024, 500, l & 15, l >> 4, tx, ty, tile);
    }
}

// ---------- generic MFMA GEMM (proven; used for act) ----------
typedef __attribute__((address_space(1))) void glb_void;
typedef __attribute__((address_space(3))) void lds_void;
__device__ __forceinline__ void dma16(const void* g, void* l) {
    __builtin_amdgcn_global_load_lds((glb_void*)(unsigned long long)(uintptr_t)g,
                                     (lds_void*)(unsigned)(uintptr_t)l, 16, 0, 0);
}

template<int RELU, typename AT>
__global__ __launch_bounds__(256)
void gemm_dma(const AT* __restrict__ A, const ushort_t* __restrict__ Bt,
              const float* __restrict__ bias, ushort_t* __restrict__ C,
              int N, int K, int Nb, int row_mul, int row_add)
{
    __shared__ __align__(16) char     AsRaw[128 * 32 * sizeof(AT)];
    __shared__ __align__(16) ushort_t Bs[128 * 32];
    const int t = threadIdx.x;
    const int lane = t & 63, w = t >> 6;
    const int bm = blockIdx.y * 128, bn = blockIdx.x * 128;
    const int mb = (w & 1) * 64, nb = (w >> 1) * 64;
    const int fr = lane & 15, fq = lane >> 4;

    f32x4 acc[16];
#pragma unroll
    for (int i = 0; i < 16; i++) acc[i] = (f32x4){0.f, 0.f, 0.f, 0.f};

    const int brow = lane >> 2, bk = lane & 3;
    const int klog = bk ^ ((brow >> 1) & 3);
    const int arow = lane >> 3, ag = lane & 7;

    for (int k0 = 0; k0 < K; k0 += 32) {
        __syncthreads();
        if constexpr (sizeof(AT) == 4) {
#pragma unroll
            for (int i = 0; i < 4; i++) {
                const int grp = w * 4 + i;
                const int row = grp * 8 + arow;
                const int gl = ag ^ (row & 7);
                dma16((const float*)A + (size_t)(bm + row) * K + k0 + gl * 4,
                      AsRaw + grp * 1024);
            }
        } else {
#pragma unroll
            for (int i = 0; i < 2; i++) {
                const int grp = w * 2 + i;
                const int row = grp * 16 + brow;
                dma16((const ushort_t*)A + (size_t)(bm + row) * K + k0 + klog * 8,
                      (ushort_t*)AsRaw + grp * 512);
            }
        }
#pragma unroll
        for (int i = 0; i < 2; i++) {
            const int grp = w * 2 + i;
            const int row = grp * 16 + brow;
            dma16(Bt + (size_t)(bn + row) * K + k0 + klog * 8, Bs + grp * 512);
        }
        __syncthreads();

        short8 af[4], bf[4];
        if constexpr (sizeof(AT) == 4) {
#pragma unroll
            for (int i = 0; i < 4; i++) {
                const int row = mb + i * 16 + fr;
                const float* base = (const float*)AsRaw + row * 32;
                const f32x4 p0 = *(const f32x4*)(base + (((2 * fq)     ^ (fr & 7)) * 4));
                const f32x4 p1 = *(const f32x4*)(base + (((2 * fq + 1) ^ (fr & 7)) * 4));
                unsigned rr[4] = { pk2bf(p0.x, p0.y), pk2bf(p0.z, p0.w),
                                   pk2bf(p1.x, p1.y), pk2bf(p1.z, p1.w) };
                af[i] = *(short8*)rr;
            }
        } else {
#pragma unroll
            for (int i = 0; i < 4; i++) {
                const int row = mb + i * 16 + fr;
                af[i] = *(const short8*)((const ushort_t*)AsRaw + row * 32 + (fq ^ ((fr >> 1) & 3)) * 8);
            }
        }
#pragma unroll
        for (int j = 0; j < 4; j++) {
            const int row = nb + j * 16 + fr;
            bf[j] = *(const short8*)(Bs + row * 32 + (fq ^ ((fr >> 1) & 3)) * 8);
        }
#pragma unroll
        for (int i = 0; i < 4; i++)
#pragma unroll
            for (int j = 0; j < 4; j++)
                acc[i * 4 + j] = __builtin_amdgcn_mfma_f32_16x16x32_bf16(
                    af[i], bf[j], acc[i * 4 + j], 0, 0, 0);
    }

#pragma unroll
    for (int j = 0; j < 4; j++) {
        const int n = bn + nb + j * 16 + fr;
        const float bv = (n < Nb) ? bias[n] : 0.f;
#pragma unroll
        for (int i = 0; i < 4; i++) {
            const f32x4 a = acc[i * 4 + j];
#pragma unroll
            for (int r = 0; r < 4; r++) {
                const int m = bm + mb + i * 16 + fq * 4 + r;
                float v = a[r] + bv;
                if (RELU) v = fmaxf(v, 0.f);
                C[((size_t)m * row_mul + row_add) * (size_t)N + n] = f2bf(v);
            }
        }
    }
}

// ---------- fc1 GEMM with fused T-mean epilogue (r3-proven) ----------
__global__ __launch_bounds__(256)
void gemm_fc1_mean(const ushort_t* __restrict__ A, const ushort_t* __restrict__ Bt,
                   const float* __restrict__ bias, float* __restrict__ cmean)
{
    __shared__ __align__(16) ushort_t AsS[128 * 32];
    __shared__ __align__(16) ushort_t Bs[128 * 32];
    const int t = threadIdx.x;
    const int lane = t & 63, w = t >> 6;
    const int bm = blockIdx.y * 128, bn = blockIdx.x * 128;
    const int mb = (w & 1) * 64, nb = (w >> 1) * 64;
    const int fr = lane & 15, fq = lane >> 4;
    const int K = 512;

    f32x4 acc[16];
#pragma unroll
    for (int i = 0; i < 16; i++) acc[i] = (f32x4){0.f, 0.f, 0.f, 0.f};

    const int brow = lane >> 2, bk = lane & 3;
    const int klog = bk ^ ((brow >> 1) & 3);

    for (int k0 = 0; k0 < K; k0 += 32) {
        __syncthreads();
#pragma unroll
        for (int i = 0; i < 2; i++) {
            const int grp = w * 2 + i;
            const int row = grp * 16 + brow;
            dma16(A + (size_t)(bm + row) * K + k0 + klog * 8, AsS + grp * 512);
        }
#pragma unroll
        for (int i = 0; i < 2; i++) {
            const int grp = w * 2 + i;
            const int row = grp * 16 + brow;
            dma16(Bt + (size_t)(bn + row) * K + k0 + klog * 8, Bs + grp * 512);
        }
        __syncthreads();

        short8 af[4], bf[4];
#pragma unroll
        for (int i = 0; i < 4; i++) {
            const int row = mb + i * 16 + fr;
            af[i] = *(const short8*)(AsS + row * 32 + (fq ^ ((fr >> 1) & 3)) * 8);
        }
#pragma unroll
        for (int j = 0; j < 4; j++) {
            const int row = nb + j * 16 + fr;
            bf[j] = *(const short8*)(Bs + row * 32 + (fq ^ ((fr >> 1) & 3)) * 8);
        }
#pragma unroll
        for (int i = 0; i < 4; i++)
#pragma unroll
            for (int j = 0; j < 4; j++)
                acc[i * 4 + j] = __builtin_amdgcn_mfma_f32_16x16x32_bf16(
                    af[i], bf[j], acc[i * 4 + j], 0, 0, 0);
    }

    const int nidx = (bm + mb) >> 6;
#pragma unroll
    for (int j = 0; j < 4; j++) {
        const int n = bn + nb + j * 16 + fr;
        const float bv = bias[n];
        float s = 0.f;
#pragma unroll
        for (int i = 0; i < 4; i++) {
            const f32x4 a = acc[i * 4 + j];
#pragma unroll
            for (int r = 0; r < 4; r++) s += fmaxf(a[r] + bv, 0.f);
        }
        s += __shfl_xor(s, 16);
        s += __shfl_xor(s, 32);
        if (fq == 0) cmean[(size_t)nidx * 1024 + n] = s * (1.0f / 64.0f);
    }
}

// ---------- MEGA: obj GEMM + graph pre + graph fin, fused ----------
// r7 change (single variable): __launch_bounds__(512, 2).  r6's plain (512)
// capped VGPRs at 128 -> acc/fin state spilled to scratch: WRITE_SIZE showed
// 19.9MB vs cbuf's 2MB (18MB = spill), and the spill reloads sat inside fin's
// dependent chain.  LDS (159KB) limits to 1 block/CU = 2 waves/SIMD anyway,
// so a 256-VGPR budget costs zero occupancy.
__global__ __launch_bounds__(512, 2)
void mega_obj_graph(const float* __restrict__ A, const ushort_t* __restrict__ Bt,
                    const float* __restrict__ bias, const ushort_t* __restrict__ act_bf,
                    const ushort_t* __restrict__ W1t, const ushort_t* __restrict__ W3t,
                    const float* __restrict__ b1, const float* __restrict__ b3,
                    const ushort_t* __restrict__ W2b, const float* __restrict__ b2,
                    const ushort_t* __restrict__ W4b, const float* __restrict__ b4,
                    ushort_t* __restrict__ cbuf)
{
    __shared__ __align__(16) ushort_t As[128 * 512];   // 128KB: A-stage -> C-stage -> fp32 handoff
    __shared__ __align__(16) float fsS[8][992];        // 31KB per-wave fin scratch

    const int t = threadIdx.x;
    const int lane = t & 63, w = t >> 6;               // w in 0..7
    const int bm = blockIdx.x * 128;
    const int fr = lane & 15, fq = lane >> 4;

    // ---- A: stage A fp32 -> bf16 LDS, (row&7) group swizzle ----
    const float4* A4 = (const float4*)(A + (size_t)bm * 512);
#pragma unroll
    for (int i = 0; i < 16; i++) {
        const int fl = i * 1024 + t * 2;
        const int row = fl >> 7;
        const float4 p0 = A4[fl];
        const float4 p1 = A4[fl + 1];
        unsigned rr[4] = { pk2bf(p0.x, p0.y), pk2bf(p0.z, p0.w),
                           pk2bf(p1.x, p1.y), pk2bf(p1.z, p1.w) };
        *(uint4*)&As[row * 512 + ((lane ^ (row & 7)) * 8)] = *(uint4*)rr;
    }

    const int nw = w * 64;
    const ushort_t* Bbase = Bt + (size_t)(nw + fr) * 512 + fq * 8;
    uint4 bA[4], bB[4];
#pragma unroll
    for (int j = 0; j < 4; j++) bA[j] = *(const uint4*)(Bbase + (size_t)j * 16 * 512);

    __syncthreads();

    // ---- B: MFMA main loop (r2-proven, B ping-pong) ----
    f32x4 acc[4][8];
#pragma unroll
    for (int j = 0; j < 4; j++)
#pragma unroll
        for (int i = 0; i < 8; i++) acc[j][i] = (f32x4){0.f, 0.f, 0.f, 0.f};

    for (int kk = 0; kk < 16; kk += 2) {
        short8 af[8];
#pragma unroll
        for (int i = 0; i < 8; i++)
            af[i] = *(const short8*)&As[(i * 16 + fr) * 512 + (((kk * 4 + fq) ^ (fr & 7)) * 8)];
#pragma unroll
        for (int j = 0; j < 4; j++) {
            bB[j] = *(const uint4*)(Bbase + (size_t)j * 16 * 512 + (kk + 1) * 32);
            const short8 bf = *(const short8*)&bA[j];
#pragma unroll
            for (int i = 0; i < 8; i++)
                acc[j][i] = __builtin_amdgcn_mfma_f32_16x16x32_bf16(af[i], bf, acc[j][i], 0, 0, 0);
        }
#pragma unroll
        for (int i = 0; i < 8; i++)
            af[i] = *(const short8*)&As[(i * 16 + fr) * 512 + ((((kk + 1) * 4 + fq) ^ (fr & 7)) * 8)];
#pragma unroll
        for (int j = 0; j < 4; j++) {
            if (kk + 2 < 16)
                bA[j] = *(const uint4*)(Bbase + (size_t)j * 16 * 512 + (kk + 2) * 32);
            const short8 bf = *(const short8*)&bB[j];
#pragma unroll
            for (int i = 0; i < 8; i++)
                acc[j][i] = __builtin_amdgcn_mfma_f32_16x16x32_bf16(af[i], bf, acc[j][i], 0, 0, 0);
        }
    }

    // ---- C: bias+relu, bf16 C-store into LDS with (m&7) group swizzle ----
    __syncthreads();
#pragma unroll
    for (int j = 0; j < 4; j++) {
        const int col0 = j * 16 + fr;
        const float bv = bias[nw + col0];
#pragma unroll
        for (int i = 0; i < 8; i++) {
#pragma unroll
            for (int rr2 = 0; rr2 < 4; rr2++) {
                const int m = i * 16 + fq * 4 + rr2;
                const int sw = ((((col0 >> 3) ^ (m & 7)) << 3) | (col0 & 7));
                As[m * 512 + nw + sw] = f2bf(fmaxf(acc[j][i][rr2] + bv, 0.f));
            }
        }
    }
    __syncthreads();

    // ---- D: inject act rows (m = ra*16+8; m&7==0 -> linear) ----
    {
        const int ra = t >> 6, gg = t & 63;
        const uint4 v = *(const uint4*)(act_bf + (size_t)(blockIdx.x * 8 + ra) * 512 + gg * 8);
        *(uint4*)&As[(ra * 16 + 8) * 512 + gg * 8] = v;
    }
    __syncthreads();

    // ---- E: per-wave pre computations into registers ----
    // w1: t1 g0-3 | w5: t1 g4-7 | w2: t3 g0-3 | w6: t3 g4-7
    // w0: S+oms g0-1 | w3: g2-3 | w4: g4-5 | w7: g6-7
    f32x4 e0[4], e1[4];
    float om0[8], om1[8];
    const bool isT = (w == 1) || (w == 2) || (w == 5) || (w == 6);
    const int gofs = (w >= 4) ? 4 : 0;
    const int sidx = (w == 0) ? 0 : (w == 3) ? 1 : (w == 4) ? 2 : 3;   // S-wave id
    const int gb = sidx * 2;

    if (isT) {
        const ushort_t* Wt = ((w & 3) == 1) ? W1t : W3t;
#pragma unroll
        for (int g = 0; g < 4; g++) { e0[g] = (f32x4){0.f,0.f,0.f,0.f}; e1[g] = e0[g]; }
        for (int kk = 0; kk < 16; kk++) {
            const short8 wa = *(const short8*)(Wt + (size_t)fr * 512 + kk * 32 + fq * 8);
            const short8 wb = *(const short8*)(Wt + (size_t)(16 + fr) * 512 + kk * 32 + fq * 8);
#pragma unroll
            for (int g = 0; g < 4; g++) {
                const short8 xf = *(const short8*)&As[((gofs + g) * 16 + fr) * 512 + (((kk * 4 + fq) ^ (fr & 7)) * 8)];
                e0[g] = __builtin_amdgcn_mfma_f32_16x16x32_bf16(xf, wa, e0[g], 0, 0, 0);
                e1[g] = __builtin_amdgcn_mfma_f32_16x16x32_bf16(xf, wb, e1[g], 0, 0, 0);
            }
        }
    } else {
        e0[0] = (f32x4){0.f,0.f,0.f,0.f}; e1[0] = e0[0];
        for (int kk = 0; kk < 16; kk++) {
            const short8 xf0 = *(const short8*)&As[(gb * 16 + fr) * 512 + (((kk * 4 + fq) ^ (fr & 7)) * 8)];
            const short8 xf1 = *(const short8*)&As[((gb + 1) * 16 + fr) * 512 + (((kk * 4 + fq) ^ (fr & 7)) * 8)];
            e0[0] = __builtin_amdgcn_mfma_f32_16x16x32_bf16(xf0, xf0, e0[0], 0, 0, 0);
            e1[0] = __builtin_amdgcn_mfma_f32_16x16x32_bf16(xf1, xf1, e1[0], 0, 0, 0);
        }
#pragma unroll
        for (int c = 0; c < 8; c++) { om0[c] = 0.f; om1[c] = 0.f; }
#pragma unroll
        for (int m = 0; m < 16; m++) {
            const uint4 q0 = *(const uint4*)&As[(gb * 16 + m) * 512 + ((lane ^ (m & 7)) * 8)];
            const uint4 q1 = *(const uint4*)&As[((gb + 1) * 16 + m) * 512 + ((lane ^ (m & 7)) * 8)];
            om0[0] += bflo(q0.x); om0[1] += bfhi(q0.x);
            om0[2] += bflo(q0.y); om0[3] += bfhi(q0.y);
            om0[4] += bflo(q0.z); om0[5] += bfhi(q0.z);
            om0[6] += bflo(q0.w); om0[7] += bfhi(q0.w);
            om1[0] += bflo(q1.x); om1[1] += bfhi(q1.x);
            om1[2] += bflo(q1.y); om1[3] += bfhi(q1.y);
            om1[4] += bflo(q1.z); om1[5] += bfhi(q1.z);
            om1[6] += bflo(q1.w); om1[7] += bfhi(q1.w);
        }
    }
    __syncthreads();   // all reads of C-tile done; As free for fp32 handoff

    // ---- handoff: per graph g (0..7): base g*1792: S[256] t1[512] t3[512] oms[512]
    float* Hs = (float*)As;
    if (isT) {
        const int toff = ((w & 3) == 1) ? 256 : 768;
#pragma unroll
        for (int g = 0; g < 4; g++) {
            float* dst = Hs + (gofs + g) * 1792 + toff;
#pragma unroll
            for (int i = 0; i < 4; i++) {
                const int m = fq * 4 + i;
                dst[m * 32 + fr]      = e0[g][i];
                dst[m * 32 + 16 + fr] = e1[g][i];
            }
        }
    } else {
        float* d0 = Hs + gb * 1792;
        float* d1 = Hs + (gb + 1) * 1792;
#pragma unroll
        for (int i = 0; i < 4; i++) {
            const int m = fq * 4 + i;
            d0[m * 16 + fr] = e0[0][i];
            d1[m * 16 + fr] = e1[0][i];
        }
        *(float4*)(d0 + 1280 + lane * 8)     = (float4){om0[0], om0[1], om0[2], om0[3]};
        *(float4*)(d0 + 1280 + lane * 8 + 4) = (float4){om0[4], om0[5], om0[6], om0[7]};
        *(float4*)(d1 + 1280 + lane * 8)     = (float4){om1[0], om1[1], om1[2], om1[3]};
        *(float4*)(d1 + 1280 + lane * 8 + 4) = (float4){om1[4], om1[5], om1[6], om1[7]};
    }
    __syncthreads();

    // ---- F: fin chain, one wave per graph (graph = w), r5-proven math ----
    {
        const int r = fr, q = fq;
        const float* Hg = Hs + w * 1792;                 // S at 0, t1 at 256, t3 at 768, oms at 1280
        float* fw   = fsS[w];
        float* adjS = fw;            // 16*17 = 272
        float* y2S  = fw + 272;      // 16*36 = 576
        float* dvS  = fw + 848;
        float* cAS  = fw + 864;
        float* nrmS = fw + 880;
        float* dv3S = fw + 896;
        float* cA3S = fw + 912;
        float* zc1S = fw + 928;      // 32
        float* zc4S = fw + 960;      // 32

        // P1: softmax over row r of S
        const float4 sv = *(const float4*)(Hg + r * 16 + q * 4);
        float mx = fmaxf(fmaxf(sv.x, sv.y), fmaxf(sv.z, sv.w));
        mx = fmaxf(mx, __shfl_xor(mx, 16));
        mx = fmaxf(mx, __shfl_xor(mx, 32));
        const float e0s = expf(sv.x - mx), e1s = expf(sv.y - mx);
        const float e2s = expf(sv.z - mx), e3s = expf(sv.w - mx);
        float rs = e0s + e1s + e2s + e3s;
        rs += __shfl_xor(rs, 16); rs += __shfl_xor(rs, 32);
        const float dv = rsqrtf(rs);
        if (q == 0) dvS[r] = dv;
        __syncthreads();

        // P2: adj + fused column sums cA
        float ad0, ad1, ad2, ad3;
        {
            const float4 dc = *(const float4*)&dvS[q * 4];
            ad0 = e0s * dv * dc.x; ad1 = e1s * dv * dc.y;
            ad2 = e2s * dv * dc.z; ad3 = e3s * dv * dc.w;
        }
        adjS[r * 17 + q * 4 + 0] = ad0; adjS[r * 17 + q * 4 + 1] = ad1;
        adjS[r * 17 + q * 4 + 2] = ad2; adjS[r * 17 + q * 4 + 3] = ad3;
        {
            float c0s = ad0, c1s = ad1, c2s = ad2, c3s = ad3;
#pragma unroll
            for (int m = 1; m <= 8; m <<= 1) {
                c0s += __shfl_xor(c0s, m); c1s += __shfl_xor(c1s, m);
                c2s += __shfl_xor(c2s, m); c3s += __shfl_xor(c3s, m);
            }
            if (r == 0) {
                cAS[q * 4 + 0] = c0s; cAS[q * 4 + 1] = c1s;
                cAS[q * 4 + 2] = c2s; cAS[q * 4 + 3] = c3s;
            }
        }
        __syncthreads();

        // P3: x1 = relu(adj@t1 + b1), y2 = relu(adj@t3 + b3); row r, cols q*8..+7
        const int c0 = q * 8;
        float x1v[8], y2v[8];
        {
            const float4 b1a = *(const float4*)(b1 + c0);
            const float4 b1b = *(const float4*)(b1 + c0 + 4);
            const float4 b3a = *(const float4*)(b3 + c0);
            const float4 b3b = *(const float4*)(b3 + c0 + 4);
            x1v[0]=b1a.x; x1v[1]=b1a.y; x1v[2]=b1a.z; x1v[3]=b1a.w;
            x1v[4]=b1b.x; x1v[5]=b1b.y; x1v[6]=b1b.z; x1v[7]=b1b.w;
            y2v[0]=b3a.x; y2v[1]=b3a.y; y2v[2]=b3a.z; y2v[3]=b3a.w;
            y2v[4]=b3b.x; y2v[5]=b3b.y; y2v[6]=b3b.z; y2v[7]=b3b.w;
        }
#pragma unroll
        for (int j = 0; j < 16; j++) {
            const float a = adjS[r * 17 + j];
            const float4 t1a = *(const float4*)(Hg + 256 + j * 32 + c0);
            const float4 t1b = *(const float4*)(Hg + 256 + j * 32 + c0 + 4);
            const float4 t3a = *(const float4*)(Hg + 768 + j * 32 + c0);
            const float4 t3b = *(const float4*)(Hg + 768 + j * 32 + c0 + 4);
            x1v[0] = fmaf(a, t1a.x, x1v[0]); x1v[1] = fmaf(a, t1a.y, x1v[1]);
            x1v[2] = fmaf(a, t1a.z, x1v[2]); x1v[3] = fmaf(a, t1a.w, x1v[3]);
            x1v[4] = fmaf(a, t1b.x, x1v[4]); x1v[5] = fmaf(a, t1b.y, x1v[5]);
            x1v[6] = fmaf(a, t1b.z, x1v[6]); x1v[7] = fmaf(a, t1b.w, x1v[7]);
            y2v[0] = fmaf(a, t3a.x, y2v[0]); y2v[1] = fmaf(a, t3a.y, y2v[1]);
            y2v[2] = fmaf(a, t3a.z, y2v[2]); y2v[3] = fmaf(a, t3a.w, y2v[3]);
            y2v[4] = fmaf(a, t3b.x, y2v[4]); y2v[5] = fmaf(a, t3b.y, y2v[5]);
            y2v[6] = fmaf(a, t3b.z, y2v[6]); y2v[7] = fmaf(a, t3b.w, y2v[7]);
        }
#pragma unroll
        for (int cc = 0; cc < 8; cc++) {
            x1v[cc] = fmaxf(x1v[cc], 0.f);
            y2v[cc] = fmaxf(y2v[cc], 0.f);
            y2S[r * 36 + c0 + cc] = y2v[cc];
        }
        __syncthreads();

        // P4: y22 row-dot + fused row-norm
        float yy[4] = {0.f, 0.f, 0.f, 0.f};
#pragma unroll
        for (int k4 = 0; k4 < 8; k4++) {
            const float4 yi = *(const float4*)&y2S[r * 36 + k4 * 4];
#pragma unroll
            for (int i = 0; i < 4; i++) {
                const float4 yj = *(const float4*)&y2S[(q * 4 + i) * 36 + k4 * 4];
                yy[i] = fmaf(yi.x, yj.x, yy[i]); yy[i] = fmaf(yi.y, yj.y, yy[i]);
                yy[i] = fmaf(yi.z, yj.z, yy[i]); yy[i] = fmaf(yi.w, yj.w, yy[i]);
            }
        }
        {
            float sq = 0.f;
#pragma unroll
            for (int i = 0; i < 4; i++) sq = fmaf(yy[i], yy[i], sq);
            sq += __shfl_xor(sq, 16); sq += __shfl_xor(sq, 32);
            const float nr = sqrtf(sq);
            if (q == 0) nrmS[r] = nr;
        }
        __syncthreads();

        // P5: adj3 + fused degree dv3; zc1 via row-reduce of cA*x1
        float a3[4];
        float dv3;
        {
            const float nr = nrmS[r];
            const float4 ncv = *(const float4*)&nrmS[q * 4];
            a3[0] = 1.0f + yy[0] / (nr * ncv.x);
            a3[1] = 1.0f + yy[1] / (nr * ncv.y);
            a3[2] = 1.0f + yy[2] / (nr * ncv.z);
            a3[3] = 1.0f + yy[3] / (nr * ncv.w);
            float d3 = a3[0] + a3[1] + a3[2] + a3[3];
            d3 += __shfl_xor(d3, 16); d3 += __shfl_xor(d3, 32);
            dv3 = rsqrtf(d3);
            if (q == 0) dv3S[r] = dv3;
        }
        {
            const float cAm = cAS[r];
            float zp[8];
#pragma unroll
            for (int cc = 0; cc < 8; cc++) zp[cc] = cAm * x1v[cc];
#pragma unroll
            for (int m = 1; m <= 8; m <<= 1)
#pragma unroll
                for (int cc = 0; cc < 8; cc++) zp[cc] += __shfl_xor(zp[cc], m);
            if (r == 0)
#pragma unroll
                for (int cc = 0; cc < 8; cc++) zc1S[c0 + cc] = zp[cc];
        }
        __syncthreads();

        // P6: cA3
        {
            const float4 d3c = *(const float4*)&dv3S[q * 4];
            float p0 = a3[0] * dv3 * d3c.x, p1 = a3[1] * dv3 * d3c.y;
            float p2 = a3[2] * dv3 * d3c.z, p3 = a3[3] * dv3 * d3c.w;
#pragma unroll
            for (int m = 1; m <= 8; m <<= 1) {
                p0 += __shfl_xor(p0, m); p1 += __shfl_xor(p1, m);
                p2 += __shfl_xor(p2, m); p3 += __shfl_xor(p3, m);
            }
            if (r == 0) {
                cA3S[q * 4 + 0] = p0; cA3S[q * 4 + 1] = p1;
                cA3S[q * 4 + 2] = p2; cA3S[q * 4 + 3] = p3;
            }
        }
        __syncthreads();

        // P7: zc4
        {
            const float cA3m = cA3S[r];
            float zp[8];
#pragma unroll
            for (int cc = 0; cc < 8; cc++) zp[cc] = cA3m * y2v[cc];
#pragma unroll
            for (int m = 1; m <= 8; m <<= 1)
#pragma unroll
                for (int cc = 0; cc < 8; cc++) zp[cc] += __shfl_xor(zp[cc], m);
            if (r == 0)
#pragma unroll
                for (int cc = 0; cc < 8; cc++) zc4S[c0 + cc] = zp[cc];
        }
        __syncthreads();

        // P8: GEMV over W2/W4 + combine + store
        {
            float gm[8] = {0,0,0,0,0,0,0,0};
            const ushort_t* w2p = W2b + lane * 8;
            const ushort_t* w4p = W4b + lane * 8;
#pragma unroll 8
            for (int k = 0; k < 32; k++) {
                const float z1 = zc1S[k], z4 = zc4S[k];
                const uint4 u2 = *(const uint4*)(w2p + (size_t)k * 512);
                const uint4 u4 = *(const uint4*)(w4p + (size_t)k * 512);
                gm[0] = fmaf(z1, bflo(u2.x), gm[0]); gm[0] = fmaf(z4, bflo(u4.x), gm[0]);
                gm[1] = fmaf(z1, bfhi(u2.x), gm[1]); gm[1] = fmaf(z4, bfhi(u4.x), gm[1]);
                gm[2] = fmaf(z1, bflo(u2.y), gm[2]); gm[2] = fmaf(z4, bflo(u4.y), gm[2]);
                gm[3] = fmaf(z1, bfhi(u2.y), gm[3]); gm[3] = fmaf(z4, bfhi(u4.y), gm[3]);
                gm[4] = fmaf(z1, bflo(u2.z), gm[4]); gm[4] = fmaf(z4, bflo(u4.z), gm[4]);
                gm[5] = fmaf(z1, bfhi(u2.z), gm[5]); gm[5] = fmaf(z4, bfhi(u4.z), gm[5]);
                gm[6] = fmaf(z1, bflo(u2.w), gm[6]); gm[6] = fmaf(z4, bflo(u4.w), gm[6]);
                gm[7] = fmaf(z1, bfhi(u2.w), gm[7]); gm[7] = fmaf(z4, bfhi(u4.w), gm[7]);
            }
            const float4 oma = *(const float4*)(Hg + 1280 + lane * 8);
            const float4 omb = *(const float4*)(Hg + 1280 + lane * 8 + 4);
            const float om[8] = {oma.x, oma.y, oma.z, oma.w, omb.x, omb.y, omb.z, omb.w};
            const float4 b2a = *(const float4*)(b2 + lane * 8);
            const float4 b2b = *(const float4*)(b2 + lane * 8 + 4);
            const float4 b4a = *(const float4*)(b4 + lane * 8);
            const float4 b4b = *(const float4*)(b4 + lane * 8 + 4);
            const float bs[8] = { b2a.x + b4a.x, b2a.y + b4a.y, b2a.z + b4a.z, b2a.w + b4a.w,
                                  b2b.x + b4b.x, b2b.y + b4b.y, b2b.z + b4b.z, b2b.w + b4b.w };
            ushort_t pk[8];
#pragma unroll
            for (int cc = 0; cc < 8; cc++) {
                const float gmean = 0.5f * bs[cc] + gm[cc] * (1.0f / 32.0f);
                const float feat  = 0.5f * (om[cc] * 0.0625f + gmean);
                pk[cc] = f2bf(fmaxf(feat, 0.f));
            }
            *(uint4*)(cbuf + (size_t)(blockIdx.x * 8 + w) * 512 + lane * 8) = *(uint4*)pk;
        }
    }
}

// ---------- clf GEMV on transposed W ----------
__global__ __launch_bounds__(256)
void clf_col(const float* __restrict__ cmean, const float* __restrict__ Wt,
             const float* __restrict__ clf_b, float* __restrict__ out)
{
    __shared__ float red[8][33];
    const int j = blockIdx.x;
    const int t = threadIdx.x;
    const int n = t & 31, kp = t >> 5;
    const float* cm = cmean + (size_t)n * 1024 + kp * 128;
    const float* wp = Wt + (size_t)j * 1024 + kp * 128;
    float acc = 0.f;
#pragma unroll
    for (int k = 0; k < 128; k += 4) {
        const float4 c = *(const float4*)(cm + k);
        const float4 wv = *(const float4*)(wp + k);
        acc = fmaf(c.x, wv.x, acc);
        acc = fmaf(c.y, wv.y, acc);
        acc = fmaf(c.z, wv.z, acc);
        acc = fmaf(c.w, wv.w, acc);
    }
    red[kp][n] = acc;
    __syncthreads();
    if (t < 32) {
        float s = red[0][t];
#pragma unroll
        for (int p = 1; p < 8; p++) s += red[p][t];
        out[(size_t)t * 500 + j] = s + clf_b[j];
    }
}

// ---------- launcher ----------
extern "C" void kernel_launch(void* const* d_in, const int* in_sizes, int n_in,
                              void* d_out, int out_size, void* d_ws, size_t ws_size,
                              hipStream_t stream)
{
    const float* object_raw = (const float*)d_in[0];
    const float* action_raw = (const float*)d_in[1];
    const float* W_obj = (const float*)d_in[2];
    const float* b_obj = (const float*)d_in[3];
    const float* W_act = (const float*)d_in[4];
    const float* b_act = (const float*)d_in[5];
    const float* gc1_W = (const float*)d_in[6];
    const float* gc1_b = (const float*)d_in[7];
    const float* gc2_W = (const float*)d_in[8];
    const float* gc2_b = (const float*)d_in[9];
    const float* gc3_W = (const float*)d_in[10];
    const float* gc3_b = (const float*)d_in[11];
    const float* gc4_W = (const float*)d_in[12];
    const float* gc4_b = (const float*)d_in[13];
    const float* fc1_W = (const float*)d_in[14];
    const float* fc1_b = (const float*)d_in[15];
    const float* clf_W = (const float*)d_in[16];
    const float* clf_b = (const float*)d_in[17];

    char* ws = (char*)d_ws;
    const size_t MB = 1024 * 1024;
    ushort_t* act_bf = (ushort_t*)(ws);                        // 2 MB
    ushort_t* cbuf   = (ushort_t*)(ws + 2 * MB);               // 2 MB
    float*    WclfT  = (float*)   (ws + 4 * MB);               // 2 MB
    float*    cmean  = (float*)   (ws + 6 * MB);               // 128 KB
    ushort_t* WobjT  = (ushort_t*)(ws + 7 * MB);               // 512 KB
    ushort_t* WactT  = (ushort_t*)(ws + 7 * MB + 512 * 1024);  // 512 KB
    ushort_t* fc1T   = (ushort_t*)(ws + 8 * MB);               // 1 MB
    ushort_t* W1t    = (ushort_t*)(ws + 9 * MB);
    ushort_t* W3t    = (ushort_t*)(ws + 9 * MB + 32 * 1024);
    ushort_t* W2bf   = (ushort_t*)(ws + 9 * MB + 64 * 1024);
    ushort_t* W4bf   = (ushort_t*)(ws + 9 * MB + 96 * 1024);

    // 1. weight prep
    prep_weights<<<dim3(1584), 256, 0, stream>>>(
        W_obj, WobjT, W_act, WactT, fc1_W, fc1T,
        gc1_W, W1t, gc3_W, W3t, gc2_W, W2bf, gc4_W, W4bf,
        clf_W, WclfT);

    // 2. act GEMM -> act_bf [2048][512]
    gemm_dma<1, float><<<dim3(4, 16), 256, 0, stream>>>(
        action_raw, WactT, b_act, act_bf, 512, 512, 512, 1, 0);

    // 3. MEGA: obj GEMM + graph pre + graph fin -> cbuf
    mega_obj_graph<<<dim3(256), 512, 0, stream>>>(
        object_raw, WobjT, b_obj, act_bf, W1t, W3t,
        gc1_b, gc3_b, W2bf, gc2_b, W4bf, gc4_b, cbuf);

    // 4. cmean = mean_T(relu(cbuf @ fc1_W + fc1_b))
    gemm_fc1_mean<<<dim3(8, 16), 256, 0, stream>>>(cbuf, fc1T, fc1_b, cmean);

    // 5. out = cmean @ clf_W + clf_b
    clf_col<<<dim3(500), 256, 0, stream>>>(cmean, WclfT, clf_b, (float*)d_out);
}